// Round 1
// baseline (570.454 us; speedup 1.0000x reference)
//
#include <hip/hip_runtime.h>
#include <hip/hip_bf16.h>
#include <math.h>

// ---------------------------------------------------------------------------
// DeepseekV2 MoE: T=16384 tokens, H=1024, E=8 routed (top-2) + 1 shared, I=512
// Round 5: k_gu -> 8-wave 256x256 phased schedule (T2+T3+T4+T5).
//  - BK=32, 4-deep LDS ring (128 KB), stage tile t+2 at iter t, vmcnt(8)
//    counted wait (never 0 in main loop) -> loads stay in flight across
//    barriers; two 16-MFMA setprio phases per tile with mid-tile barrier.
//  - Pair-packed XOR swizzle: rows 2j,2j+1 share a 128B line, slot
//    (r0*4+c)^(j&7); swizzle applied at the global source, LDS dest linear.
//  k_down_s / k_down_r / gate / transposes unchanged this round.
// ---------------------------------------------------------------------------

#define T_TOTAL 16384
#define HDIM 1024
#define IDIM 512
#define NE 9  // 8 routed + 1 shared (expert index 8)
#define CNT_STRIDE 16

typedef __bf16 bf16x8 __attribute__((ext_vector_type(8)));
typedef float f32x4 __attribute__((ext_vector_type(4)));

typedef __attribute__((address_space(1))) void gvoid_t;
typedef __attribute__((address_space(3))) void lvoid_t;

__device__ __forceinline__ void load_lds16(const void* g, void* l) {
  // 16B/lane; LDS dest = wave-uniform base + lane*16 (global src may scatter)
  __builtin_amdgcn_global_load_lds((const gvoid_t*)g, (lvoid_t*)l, 16, 0, 0);
}

__device__ __forceinline__ f32x4 mfma_bf16(bf16x8 a, bf16x8 b, f32x4 c) {
  return __builtin_amdgcn_mfma_f32_16x16x32_bf16(a, b, c, 0, 0, 0);
}

// ---------------------------------------------------------------------------
// Gate (unchanged): block-aggregated slot assignment.
// ---------------------------------------------------------------------------
__global__ __launch_bounds__(256) void k_gate(const float* __restrict__ x,
                                              const float* __restrict__ gw,
                                              __bf16* __restrict__ xb,
                                              int* __restrict__ tok,
                                              float* __restrict__ wtl,
                                              int* __restrict__ cnt) {
  __shared__ int s_eid[64][2];
  __shared__ float s_wt[64][2];
  __shared__ int s_rank[64][2];
  __shared__ int lcnt[8];
  __shared__ int lbase[8];
  const int wv = threadIdx.x >> 6, lane = threadIdx.x & 63;
  if (threadIdx.x < 8) lcnt[threadIdx.x] = 0;
  __syncthreads();

  for (int i = 0; i < 16; i++) {
    const int tl = wv * 16 + i;
    const int t = blockIdx.x * 64 + tl;
    const float* xr = x + (size_t)t * HDIM + lane * 16;
    float4 xv[4];
#pragma unroll
    for (int j = 0; j < 4; j++) xv[j] = ((const float4*)xr)[j];

    bf16x8 v0, v1;
#pragma unroll
    for (int j = 0; j < 8; j++) v0[j] = (__bf16)((const float*)xv)[j];
#pragma unroll
    for (int j = 0; j < 8; j++) v1[j] = (__bf16)((const float*)xv)[j + 8];
    bf16x8* xbo = (bf16x8*)(xb + (size_t)t * HDIM + lane * 16);
    xbo[0] = v0;
    xbo[1] = v1;

    float acc[8];
#pragma unroll
    for (int e = 0; e < 8; e++) {
      const float4* gp = (const float4*)(gw + e * HDIM + lane * 16);
      float s = 0.f;
#pragma unroll
      for (int j = 0; j < 4; j++) {
        float4 g = gp[j];
        s += xv[j].x * g.x + xv[j].y * g.y + xv[j].z * g.z + xv[j].w * g.w;
      }
      acc[e] = s;
    }
#pragma unroll
    for (int d = 32; d >= 1; d >>= 1) {
#pragma unroll
      for (int e = 0; e < 8; e++) acc[e] += __shfl_xor(acc[e], d, 64);
    }
    if (lane == 0) {
      float mx = acc[0];
#pragma unroll
      for (int e = 1; e < 8; e++) mx = fmaxf(mx, acc[e]);
      float p[8], Z = 0.f;
#pragma unroll
      for (int e = 0; e < 8; e++) {
        p[e] = expf(acc[e] - mx);
        Z += p[e];
      }
#pragma unroll
      for (int e = 0; e < 8; e++) p[e] /= Z;
      int i1 = 0;
#pragma unroll
      for (int e = 1; e < 8; e++)
        if (p[e] > p[i1]) i1 = e;
      int i2 = (i1 == 0) ? 1 : 0;
#pragma unroll
      for (int e = 0; e < 8; e++)
        if (e != i1 && p[e] > p[i2]) i2 = e;
      const float s12 = p[i1] + p[i2] + 1e-20f;
      s_eid[tl][0] = i1;
      s_eid[tl][1] = i2;
      s_wt[tl][0] = p[i1] / s12;
      s_wt[tl][1] = p[i2] / s12;
    }
  }
  __syncthreads();

  if (threadIdx.x < 64) {
    s_rank[threadIdx.x][0] = atomicAdd(&lcnt[s_eid[threadIdx.x][0]], 1);
    s_rank[threadIdx.x][1] = atomicAdd(&lcnt[s_eid[threadIdx.x][1]], 1);
  }
  __syncthreads();
  if (threadIdx.x < 8)
    lbase[threadIdx.x] =
        atomicAdd(&cnt[threadIdx.x * CNT_STRIDE], lcnt[threadIdx.x]);
  __syncthreads();
  if (threadIdx.x < 64) {
    const int t = blockIdx.x * 64 + threadIdx.x;
#pragma unroll
    for (int j = 0; j < 2; j++) {
      const int e = s_eid[threadIdx.x][j];
      const int slot = lbase[e] + s_rank[threadIdx.x][j];
      tok[e * T_TOTAL + slot] = t;
      wtl[e * T_TOTAL + slot] = s_wt[threadIdx.x][j];
    }
  }
}

// ---------------------------------------------------------------------------
// Plain transpose+cast (for Wd): src fp32 [R][C] -> out bf16 [b][C][R]
// ---------------------------------------------------------------------------
__global__ __launch_bounds__(256) void k_transpose(const float* __restrict__ w8,
                                                   const float* __restrict__ w1,
                                                   __bf16* __restrict__ out,
                                                   int R, int C) {
  __shared__ float tile[32][33];
  const int b = blockIdx.z;
  const float* src = (b < 8) ? (w8 + (size_t)b * R * C) : w1;
  const int c0 = blockIdx.x * 32, r0 = blockIdx.y * 32;
  const int tx = threadIdx.x & 31, ty = threadIdx.x >> 5;
#pragma unroll
  for (int i = 0; i < 4; i++)
    tile[ty + i * 8][tx] = src[(size_t)(r0 + ty + i * 8) * C + c0 + tx];
  __syncthreads();
#pragma unroll
  for (int i = 0; i < 4; i++)
    out[(size_t)b * R * C + (size_t)(c0 + ty + i * 8) * R + r0 + tx] =
        (__bf16)tile[tx][ty + i * 8];
}

// ---------------------------------------------------------------------------
// Fused-GU transpose: src fp32 [b][1024 h][512 i] -> Wfu bf16 [b][1024 f][1024 h]
// fused row f(i) = 2*(i & ~15) + (i & 15) + u16off  (u16off: 0 for G, 16 for U)
// ---------------------------------------------------------------------------
__global__ __launch_bounds__(256) void k_transpose_fuse(
    const float* __restrict__ w8, const float* __restrict__ w1,
    __bf16* __restrict__ out, int u16off) {
  __shared__ float tile[32][33];
  const int b = blockIdx.z;
  const float* src = (b < 8) ? (w8 + (size_t)b * HDIM * IDIM) : w1;
  const int c0 = blockIdx.x * 32, r0 = blockIdx.y * 32;  // c=i, r=h
  const int tx = threadIdx.x & 31, ty = threadIdx.x >> 5;
#pragma unroll
  for (int i = 0; i < 4; i++)
    tile[ty + i * 8][tx] = src[(size_t)(r0 + ty + i * 8) * IDIM + c0 + tx];
  __syncthreads();
#pragma unroll
  for (int i = 0; i < 4; i++) {
    const int ic = c0 + ty + i * 8;
    const int f = 2 * (ic & ~15) + (ic & 15) + u16off;
    out[(size_t)b * 1024 * HDIM + (size_t)f * HDIM + r0 + tx] =
        (__bf16)tile[tx][ty + i * 8];
  }
}

// ---------------------------------------------------------------------------
// Phase A (sparse, fused): 256x256 tile, 8 waves, phased pipeline.
// Tile t in LDS buffer t&3 (4-deep ring). K=1024 -> 32 K-tiles of 32.
// acc[m][2p]=G, acc[m][2p+1]=U; i-col = (n0+wn)/2 + p*16 + l16.
// ---------------------------------------------------------------------------
__global__ __launch_bounds__(512, 2) void k_gu(
    const __bf16* __restrict__ xb, const __bf16* __restrict__ Wfu,
    const int* __restrict__ tok, const float* __restrict__ wtl,
    const int* __restrict__ cnt, __bf16* __restrict__ inter) {
  const int e = blockIdx.z;
  const bool se = (e == 8);
  const int cnt_e = se ? T_TOTAL : cnt[e * CNT_STRIDE];
  const int m0 = blockIdx.x * 256;
  if (m0 >= cnt_e) return;  // uniform early-exit before any barrier

  __shared__ char ldsA[65536];  // 4 bufs x 16 KB (256 rows x 32 cols bf16)
  __shared__ char ldsB[65536];

  const int tid = threadIdx.x;
  const int w = tid >> 6, lane = tid & 63;
  const int quad = lane >> 4, l16 = lane & 15;
  const int wm = (w & 1) * 128, wn = (w >> 1) * 64;  // 2M x 4N waves
  const int n0 = blockIdx.y * 256;
  const int wofs = w * 1024;

  // staging source coords: line = pair of rows (128B); slot holds global
  // chunk (r0*4+c)^(line&7)  ->  pre-swizzle the SOURCE, keep dest linear.
  const int ln = tid >> 3;                // line within 8KB shot (0..63)
  const int sp = (tid & 7) ^ (ln & 7);    // swizzled slot index
  const int r0 = sp >> 2, ccol = sp & 3;  // row-in-pair, 16B chunk

  const __bf16* apc0;
  const __bf16* apc1;
  const __bf16* bpc0;
  const __bf16* bpc1;
  {
    int s0 = m0 + 2 * ln + r0;
    if (s0 > cnt_e - 1) s0 = cnt_e - 1;
    int s1 = m0 + 128 + 2 * ln + r0;
    if (s1 > cnt_e - 1) s1 = cnt_e - 1;
    const int t0 = se ? s0 : tok[e * T_TOTAL + s0];
    const int t1 = se ? s1 : tok[e * T_TOTAL + s1];
    apc0 = xb + (size_t)t0 * HDIM + ccol * 8;
    apc1 = xb + (size_t)t1 * HDIM + ccol * 8;
    bpc0 = Wfu + ((size_t)e * 1024 + n0 + 2 * ln + r0) * HDIM + ccol * 8;
    bpc1 = Wfu + ((size_t)e * 1024 + n0 + 128 + 2 * ln + r0) * HDIM + ccol * 8;
  }

  f32x4 acc[8][4];
#pragma unroll
  for (int m = 0; m < 8; m++)
#pragma unroll
    for (int n = 0; n < 4; n++) acc[m][n] = {0.f, 0.f, 0.f, 0.f};

  auto stage = [&](int tt) {
    char* dA = ldsA + (tt & 3) * 16384 + wofs;
    char* dB = ldsB + (tt & 3) * 16384 + wofs;
    load_lds16(apc0, dA);
    load_lds16(apc1, dA + 8192);
    load_lds16(bpc0, dB);
    load_lds16(bpc1, dB + 8192);
    apc0 += 32;
    apc1 += 32;
    bpc0 += 32;
    bpc1 += 32;
  };

  // frag slot: j&7 == l16>>1 for every frag row (wm,wn,m*16 all ≡0 mod 16)
  const int so16 = ((((l16 & 1) << 2) + quad) ^ (l16 >> 1)) * 16;

  auto compute = [&](int tt) {
    const char* bA = ldsA + (tt & 3) * 16384;
    const char* bB = ldsB + (tt & 3) * 16384;
    bf16x8 bfr[4], af[4];
#pragma unroll
    for (int n = 0; n < 4; ++n) {
      const int j = (wn + n * 16 + l16) >> 1;
      bfr[n] = *(const bf16x8*)(bB + j * 128 + so16);
    }
#pragma unroll
    for (int m = 0; m < 4; ++m) {
      const int j = (wm + m * 16 + l16) >> 1;
      af[m] = *(const bf16x8*)(bA + j * 128 + so16);
    }
    __builtin_amdgcn_s_setprio(1);
#pragma unroll
    for (int m = 0; m < 4; ++m)
#pragma unroll
      for (int n = 0; n < 4; ++n)
        acc[m][n] = mfma_bf16(af[m], bfr[n], acc[m][n]);
    __builtin_amdgcn_s_setprio(0);
    __builtin_amdgcn_s_barrier();  // mid-tile lockstep
#pragma unroll
    for (int m = 0; m < 4; ++m) {
      const int j = (wm + 64 + m * 16 + l16) >> 1;
      af[m] = *(const bf16x8*)(bA + j * 128 + so16);
    }
    __builtin_amdgcn_s_setprio(1);
#pragma unroll
    for (int m = 0; m < 4; ++m)
#pragma unroll
      for (int n = 0; n < 4; ++n)
        acc[4 + m][n] = mfma_bf16(af[m], bfr[n], acc[4 + m][n]);
    __builtin_amdgcn_s_setprio(0);
  };

  // prologue: tiles 0,1 in flight
  stage(0);
  stage(1);
  // main loop: stage t+2, counted wait (tile t's 4 loads are the oldest;
  // the 8 loads for t+1/t+2 stay in flight across the barriers)
  for (int t = 0; t < 30; ++t) {
    stage(t + 2);
    asm volatile("s_waitcnt vmcnt(8)" ::: "memory");
    __builtin_amdgcn_s_barrier();
    compute(t);
  }
  asm volatile("s_waitcnt vmcnt(4)" ::: "memory");
  __builtin_amdgcn_s_barrier();
  compute(30);
  asm volatile("s_waitcnt vmcnt(0)" ::: "memory");
  __builtin_amdgcn_s_barrier();
  compute(31);

  // epilogue: C/D col=lane&15, row=quad*4+r; G/U pairs in even/odd n-frags
#pragma unroll
  for (int m = 0; m < 8; ++m) {
#pragma unroll
    for (int r = 0; r < 4; ++r) {
      const int slot = m0 + wm + m * 16 + quad * 4 + r;
      if (slot < cnt_e) {
        const float wt = se ? 1.0f : wtl[e * T_TOTAL + slot];
        __bf16* op = inter + ((size_t)e * T_TOTAL + slot) * IDIM +
                     ((n0 + wn) >> 1) + l16;
#pragma unroll
        for (int p = 0; p < 2; ++p) {
          const float g = acc[m][2 * p][r];
          const float u = acc[m][2 * p + 1][r];
          const float v =
              wt * u * 0.5f * g * (1.0f + erff(g * 0.70710678118654752f));
          op[p * 16] = (__bf16)v;
        }
      }
    }
  }
}

// ---------------------------------------------------------------------------
// Phase B shared: out[T][H] = inter[8] @ Wd[8]  (plain stores, runs first)
// ---------------------------------------------------------------------------
__global__ __launch_bounds__(256, 2) void k_down_s(const __bf16* __restrict__ iA,
                                                   const __bf16* __restrict__ wB,
                                                   float* __restrict__ out) {
  __shared__ __bf16 sA[128][64];
  __shared__ __bf16 sB[128][64];
  const int tid = threadIdx.x, w = tid >> 6, lane = tid & 63;
  const int m0 = blockIdx.x * 128, n0 = blockIdx.y * 128;
  const int quad = lane >> 4, l16 = lane & 15;
  const int wm = (w & 1) * 64, wn = (w >> 1) * 64;

  const int sr = tid >> 3;
  const int scs = ((tid & 7) ^ (sr & 7)) * 8;
  const __bf16* ap[4];
  const __bf16* bp[4];
#pragma unroll
  for (int sh = 0; sh < 4; sh++) {
    ap[sh] = iA + (size_t)(m0 + sh * 32 + sr) * IDIM + scs;
    bp[sh] = wB + (size_t)(n0 + sh * 32 + sr) * IDIM + scs;
  }
  char* const la = (char*)sA + w * 1024;
  char* const lb = (char*)sB + w * 1024;

  f32x4 acc[4][4];
#pragma unroll
  for (int im = 0; im < 4; im++)
#pragma unroll
    for (int in = 0; in < 4; in++) acc[im][in] = {0.f, 0.f, 0.f, 0.f};

  for (int k = 0; k < IDIM; k += 64) {
    __syncthreads();
#pragma unroll
    for (int sh = 0; sh < 4; sh++) {
      load_lds16(ap[sh], la + sh * 4096);
      load_lds16(bp[sh], lb + sh * 4096);
      ap[sh] += 64;
      bp[sh] += 64;
    }
    __syncthreads();
#pragma unroll
    for (int kh = 0; kh < 2; kh++) {
      bf16x8 af[4], bfr[4];
#pragma unroll
      for (int i = 0; i < 4; i++) {
        const int ra = wm + i * 16 + l16;
        af[i] = *(const bf16x8*)((const char*)sA + ra * 128 +
                                 ((kh * 4 + quad) ^ (ra & 7)) * 16);
        const int rb = wn + i * 16 + l16;
        bfr[i] = *(const bf16x8*)((const char*)sB + rb * 128 +
                                  ((kh * 4 + quad) ^ (rb & 7)) * 16);
      }
#pragma unroll
      for (int im = 0; im < 4; im++)
#pragma unroll
        for (int in = 0; in < 4; in++)
          acc[im][in] = mfma_bf16(af[im], bfr[in], acc[im][in]);
    }
  }

#pragma unroll
  for (int im = 0; im < 4; im++) {
#pragma unroll
    for (int r = 0; r < 4; r++) {
      const int t = m0 + wm + im * 16 + quad * 4 + r;
#pragma unroll
      for (int in = 0; in < 4; in++)
        out[(size_t)t * HDIM + n0 + wn + in * 16 + l16] = acc[im][in][r];
    }
  }
}

// ---------------------------------------------------------------------------
// Phase B routed: per expert e, gathered GEMM inter[e][0..cnt) @ Wd[e],
// atomic scatter-add into out (after k_down_s initialized it).
// ---------------------------------------------------------------------------
__global__ __launch_bounds__(256, 2) void k_down_r(
    const __bf16* __restrict__ inter, const __bf16* __restrict__ WdT,
    const int* __restrict__ tok, const int* __restrict__ cnt,
    float* __restrict__ out) {
  const int e = blockIdx.z;
  const int cnt_e = cnt[e * CNT_STRIDE];
  const int m0 = blockIdx.x * 128;
  if (m0 >= cnt_e) return;

  __shared__ __bf16 sA[128][64];
  __shared__ __bf16 sB[128][64];
  const int tid = threadIdx.x, w = tid >> 6, lane = tid & 63;
  const int n0 = blockIdx.y * 128;
  const int quad = lane >> 4, l16 = lane & 15;
  const int wm = (w & 1) * 64, wn = (w >> 1) * 64;

  const int sr = tid >> 3;
  const int scs = ((tid & 7) ^ (sr & 7)) * 8;
  const __bf16* ap[4];
  const __bf16* bp[4];
#pragma unroll
  for (int sh = 0; sh < 4; sh++) {
    int s = m0 + sh * 32 + sr;
    if (s > cnt_e - 1) s = cnt_e - 1;
    ap[sh] = inter + ((size_t)e * T_TOTAL + s) * IDIM + scs;
    bp[sh] = WdT + ((size_t)e * HDIM + n0 + sh * 32 + sr) * IDIM + scs;
  }
  char* const la = (char*)sA + w * 1024;
  char* const lb = (char*)sB + w * 1024;

  f32x4 acc[4][4];
#pragma unroll
  for (int im = 0; im < 4; im++)
#pragma unroll
    for (int in = 0; in < 4; in++) acc[im][in] = {0.f, 0.f, 0.f, 0.f};

  for (int k = 0; k < IDIM; k += 64) {
    __syncthreads();
#pragma unroll
    for (int sh = 0; sh < 4; sh++) {
      load_lds16(ap[sh], la + sh * 4096);
      load_lds16(bp[sh], lb + sh * 4096);
      ap[sh] += 64;
      bp[sh] += 64;
    }
    __syncthreads();
#pragma unroll
    for (int kh = 0; kh < 2; kh++) {
      bf16x8 af[4], bfr[4];
#pragma unroll
      for (int i = 0; i < 4; i++) {
        const int ra = wm + i * 16 + l16;
        af[i] = *(const bf16x8*)((const char*)sA + ra * 128 +
                                 ((kh * 4 + quad) ^ (ra & 7)) * 16);
        const int rb = wn + i * 16 + l16;
        bfr[i] = *(const bf16x8*)((const char*)sB + rb * 128 +
                                  ((kh * 4 + quad) ^ (rb & 7)) * 16);
      }
#pragma unroll
      for (int im = 0; im < 4; im++)
#pragma unroll
        for (int in = 0; in < 4; in++)
          acc[im][in] = mfma_bf16(af[im], bfr[in], acc[im][in]);
    }
  }

#pragma unroll
  for (int im = 0; im < 4; im++) {
#pragma unroll
    for (int r = 0; r < 4; r++) {
      const int slot = m0 + wm + im * 16 + quad * 4 + r;
      if (slot < cnt_e) {
        const int t = tok[e * T_TOTAL + slot];
#pragma unroll
        for (int in = 0; in < 4; in++)
          atomicAdd(&out[(size_t)t * HDIM + n0 + wn + in * 16 + l16],
                    acc[im][in][r]);
      }
    }
  }
}

// ---------------------------------------------------------------------------
extern "C" void kernel_launch(void* const* d_in, const int* in_sizes, int n_in,
                              void* d_out, int out_size, void* d_ws,
                              size_t ws_size, hipStream_t stream) {
  const float* x = (const float*)d_in[0];
  const float* gw = (const float*)d_in[1];
  const float* Wg = (const float*)d_in[2];
  const float* Wu = (const float*)d_in[3];
  const float* Wd = (const float*)d_in[4];
  const float* sWg = (const float*)d_in[5];
  const float* sWu = (const float*)d_in[6];
  const float* sWd = (const float*)d_in[7];
  float* out = (float*)d_out;

  char* ws = (char*)d_ws;
  size_t off = 0;
  auto alloc = [&](size_t n) {
    char* p = ws + off;
    off += (n + 255) & ~(size_t)255;
    return p;
  };
  __bf16* xb = (__bf16*)alloc((size_t)T_TOTAL * HDIM * 2);          // 33.5 MB
  __bf16* Wfu = (__bf16*)alloc((size_t)NE * 1024 * HDIM * 2);       // 18.9 MB
  __bf16* WdT = (__bf16*)alloc((size_t)NE * HDIM * IDIM * 2);       // 9.4 MB
  int* tok = (int*)alloc((size_t)8 * T_TOTAL * 4);                  // 512 KB
  float* wtl = (float*)alloc((size_t)8 * T_TOTAL * 4);              // 512 KB
  int* cnt = (int*)alloc(8 * CNT_STRIDE * 4);
  __bf16* inter = (__bf16*)alloc((size_t)NE * T_TOTAL * IDIM * 2);  // 151 MB

  hipMemsetAsync(cnt, 0, 8 * CNT_STRIDE * 4, stream);

  k_gate<<<dim3(T_TOTAL / 64), dim3(256), 0, stream>>>(x, gw, xb, tok, wtl,
                                                       cnt);
  // Wg/sWg -> fused rows +0 (G), Wu/sWu -> fused rows +16 (U)
  k_transpose_fuse<<<dim3(IDIM / 32, HDIM / 32, NE), dim3(256), 0, stream>>>(
      Wg, sWg, Wfu, 0);
  k_transpose_fuse<<<dim3(IDIM / 32, HDIM / 32, NE), dim3(256), 0, stream>>>(
      Wu, sWu, Wfu, 16);
  // Wd [8][I][H] + sWd [I][H] -> WdT [9][H][I]
  k_transpose<<<dim3(HDIM / 32, IDIM / 32, NE), dim3(256), 0, stream>>>(
      Wd, sWd, WdT, IDIM, HDIM);

  // Phase A: fused GU, 256x256 tiles, 8 waves; worst-case x grid, early-exit.
  k_gu<<<dim3(T_TOTAL / 256, 1024 / 256, NE), dim3(512), 0, stream>>>(
      xb, Wfu, tok, wtl, cnt, inter);

  // Phase B: shared expert first (plain stores initialize out) ...
  k_down_s<<<dim3(T_TOTAL / 128, HDIM / 128), dim3(256), 0, stream>>>(
      inter + (size_t)8 * T_TOTAL * IDIM, WdT + (size_t)8 * HDIM * IDIM, out);
  // ... then routed experts atomic-add on top.
  k_down_r<<<dim3(T_TOTAL / 128, HDIM / 128, 8), dim3(256), 0, stream>>>(
      inter, WdT, tok, cnt, out);
}

// Round 2
// 552.217 us; speedup vs baseline: 1.0330x; 1.0330x over previous
//
#include <hip/hip_runtime.h>
#include <hip/hip_bf16.h>
#include <math.h>

// ---------------------------------------------------------------------------
// DeepseekV2 MoE: T=16384 tokens, H=1024, E=8 routed (top-2) + 1 shared, I=512
// Round 6: k_gu -> faithful m201-style 8-phase schedule.
//  - BM=BN=256, BK=64, 16 K-tiles x 4 phases (16 MFMA each, quadrant = kk x m-half).
//  - LDS = 8 regions (A/B x K-half x parity) x 16KB. Stage 1 region (2x
//    global_load_lds) per phase; counted vmcnt(8) at phases 2&4 (never 0 in
//    main loop); tail peels with vmcnt(4)/vmcnt(0). setprio around each
//    16-MFMA cluster. Ledger-verified WAR/RAW per region.
//  - Swizzle: LDS chunk = quad ^ ((row>>1)&3) -> 2-way (free); applied at
//    the global SOURCE for staging (linear wave-uniform LDS dest).
//  k_down_s / k_down_r / gate / transposes unchanged (round-4 state).
// ---------------------------------------------------------------------------

#define T_TOTAL 16384
#define HDIM 1024
#define IDIM 512
#define NE 9  // 8 routed + 1 shared (expert index 8)
#define CNT_STRIDE 16

typedef __bf16 bf16x8 __attribute__((ext_vector_type(8)));
typedef float f32x4 __attribute__((ext_vector_type(4)));

typedef __attribute__((address_space(1))) void gvoid_t;
typedef __attribute__((address_space(3))) void lvoid_t;

__device__ __forceinline__ void load_lds16(const void* g, void* l) {
  // 16B/lane; LDS dest = wave-uniform base + lane*16 (global src may scatter)
  __builtin_amdgcn_global_load_lds((const gvoid_t*)g, (lvoid_t*)l, 16, 0, 0);
}

__device__ __forceinline__ f32x4 mfma_bf16(bf16x8 a, bf16x8 b, f32x4 c) {
  return __builtin_amdgcn_mfma_f32_16x16x32_bf16(a, b, c, 0, 0, 0);
}

// ---------------------------------------------------------------------------
// Gate (unchanged): block-aggregated slot assignment.
// ---------------------------------------------------------------------------
__global__ __launch_bounds__(256) void k_gate(const float* __restrict__ x,
                                              const float* __restrict__ gw,
                                              __bf16* __restrict__ xb,
                                              int* __restrict__ tok,
                                              float* __restrict__ wtl,
                                              int* __restrict__ cnt) {
  __shared__ int s_eid[64][2];
  __shared__ float s_wt[64][2];
  __shared__ int s_rank[64][2];
  __shared__ int lcnt[8];
  __shared__ int lbase[8];
  const int wv = threadIdx.x >> 6, lane = threadIdx.x & 63;
  if (threadIdx.x < 8) lcnt[threadIdx.x] = 0;
  __syncthreads();

  for (int i = 0; i < 16; i++) {
    const int tl = wv * 16 + i;
    const int t = blockIdx.x * 64 + tl;
    const float* xr = x + (size_t)t * HDIM + lane * 16;
    float4 xv[4];
#pragma unroll
    for (int j = 0; j < 4; j++) xv[j] = ((const float4*)xr)[j];

    bf16x8 v0, v1;
#pragma unroll
    for (int j = 0; j < 8; j++) v0[j] = (__bf16)((const float*)xv)[j];
#pragma unroll
    for (int j = 0; j < 8; j++) v1[j] = (__bf16)((const float*)xv)[j + 8];
    bf16x8* xbo = (bf16x8*)(xb + (size_t)t * HDIM + lane * 16);
    xbo[0] = v0;
    xbo[1] = v1;

    float acc[8];
#pragma unroll
    for (int e = 0; e < 8; e++) {
      const float4* gp = (const float4*)(gw + e * HDIM + lane * 16);
      float s = 0.f;
#pragma unroll
      for (int j = 0; j < 4; j++) {
        float4 g = gp[j];
        s += xv[j].x * g.x + xv[j].y * g.y + xv[j].z * g.z + xv[j].w * g.w;
      }
      acc[e] = s;
    }
#pragma unroll
    for (int d = 32; d >= 1; d >>= 1) {
#pragma unroll
      for (int e = 0; e < 8; e++) acc[e] += __shfl_xor(acc[e], d, 64);
    }
    if (lane == 0) {
      float mx = acc[0];
#pragma unroll
      for (int e = 1; e < 8; e++) mx = fmaxf(mx, acc[e]);
      float p[8], Z = 0.f;
#pragma unroll
      for (int e = 0; e < 8; e++) {
        p[e] = expf(acc[e] - mx);
        Z += p[e];
      }
#pragma unroll
      for (int e = 0; e < 8; e++) p[e] /= Z;
      int i1 = 0;
#pragma unroll
      for (int e = 1; e < 8; e++)
        if (p[e] > p[i1]) i1 = e;
      int i2 = (i1 == 0) ? 1 : 0;
#pragma unroll
      for (int e = 0; e < 8; e++)
        if (e != i1 && p[e] > p[i2]) i2 = e;
      const float s12 = p[i1] + p[i2] + 1e-20f;
      s_eid[tl][0] = i1;
      s_eid[tl][1] = i2;
      s_wt[tl][0] = p[i1] / s12;
      s_wt[tl][1] = p[i2] / s12;
    }
  }
  __syncthreads();

  if (threadIdx.x < 64) {
    s_rank[threadIdx.x][0] = atomicAdd(&lcnt[s_eid[threadIdx.x][0]], 1);
    s_rank[threadIdx.x][1] = atomicAdd(&lcnt[s_eid[threadIdx.x][1]], 1);
  }
  __syncthreads();
  if (threadIdx.x < 8)
    lbase[threadIdx.x] =
        atomicAdd(&cnt[threadIdx.x * CNT_STRIDE], lcnt[threadIdx.x]);
  __syncthreads();
  if (threadIdx.x < 64) {
    const int t = blockIdx.x * 64 + threadIdx.x;
#pragma unroll
    for (int j = 0; j < 2; j++) {
      const int e = s_eid[threadIdx.x][j];
      const int slot = lbase[e] + s_rank[threadIdx.x][j];
      tok[e * T_TOTAL + slot] = t;
      wtl[e * T_TOTAL + slot] = s_wt[threadIdx.x][j];
    }
  }
}

// ---------------------------------------------------------------------------
// Plain transpose+cast (for Wd): src fp32 [R][C] -> out bf16 [b][C][R]
// ---------------------------------------------------------------------------
__global__ __launch_bounds__(256) void k_transpose(const float* __restrict__ w8,
                                                   const float* __restrict__ w1,
                                                   __bf16* __restrict__ out,
                                                   int R, int C) {
  __shared__ float tile[32][33];
  const int b = blockIdx.z;
  const float* src = (b < 8) ? (w8 + (size_t)b * R * C) : w1;
  const int c0 = blockIdx.x * 32, r0 = blockIdx.y * 32;
  const int tx = threadIdx.x & 31, ty = threadIdx.x >> 5;
#pragma unroll
  for (int i = 0; i < 4; i++)
    tile[ty + i * 8][tx] = src[(size_t)(r0 + ty + i * 8) * C + c0 + tx];
  __syncthreads();
#pragma unroll
  for (int i = 0; i < 4; i++)
    out[(size_t)b * R * C + (size_t)(c0 + ty + i * 8) * R + r0 + tx] =
        (__bf16)tile[tx][ty + i * 8];
}

// ---------------------------------------------------------------------------
// Fused-GU transpose: src fp32 [b][1024 h][512 i] -> Wfu bf16 [b][1024 f][1024 h]
// fused row f(i) = 2*(i & ~15) + (i & 15) + u16off  (u16off: 0 for G, 16 for U)
// ---------------------------------------------------------------------------
__global__ __launch_bounds__(256) void k_transpose_fuse(
    const float* __restrict__ w8, const float* __restrict__ w1,
    __bf16* __restrict__ out, int u16off) {
  __shared__ float tile[32][33];
  const int b = blockIdx.z;
  const float* src = (b < 8) ? (w8 + (size_t)b * HDIM * IDIM) : w1;
  const int c0 = blockIdx.x * 32, r0 = blockIdx.y * 32;  // c=i, r=h
  const int tx = threadIdx.x & 31, ty = threadIdx.x >> 5;
#pragma unroll
  for (int i = 0; i < 4; i++)
    tile[ty + i * 8][tx] = src[(size_t)(r0 + ty + i * 8) * IDIM + c0 + tx];
  __syncthreads();
#pragma unroll
  for (int i = 0; i < 4; i++) {
    const int ic = c0 + ty + i * 8;
    const int f = 2 * (ic & ~15) + (ic & 15) + u16off;
    out[(size_t)b * 1024 * HDIM + (size_t)f * HDIM + r0 + tx] =
        (__bf16)tile[tx][ty + i * 8];
  }
}

// ---------------------------------------------------------------------------
// Phase A (sparse, fused): 256x256 tile, 8 waves (2M x 4N), m201-style
// 4-phase-per-K-tile pipeline with counted vmcnt.
// Regions: lds{A,B} + par*32768 + kh*16384; region = 256 rows x 32 cols bf16,
// row stride 64B, chunk(16B) swizzle: lds_chunk = global_chunk ^ ((row>>1)&3).
// Stage ledger (phase p of K-tile k):
//   ph1: stage (A,kh1,k+1)   ph2: stage (B,kh1,k+1), vmcnt(8)
//   ph3: stage (A,kh0,k+2)   ph4: stage (B,kh0,k+2), vmcnt(8)
// Reads: ph1/2 consume (A/B,kh0,k) [staged k-2.ph3/4, protected k-1.ph4 vmcnt]
//        ph3/4 consume (A/B,kh1,k) [staged k-1.ph1/2, protected k.ph2 vmcnt]
// ---------------------------------------------------------------------------
#define VM8A asm volatile("s_waitcnt vmcnt(8)" ::: "memory")
#define VM4A asm volatile("s_waitcnt vmcnt(4)" ::: "memory")
#define VM0A asm volatile("s_waitcnt vmcnt(0)" ::: "memory")
#define GUNOP ((void)0)

#define GUST_A0(PAR)                              \
  {                                               \
    char* d = stA + (PAR) * 32768;                \
    load_lds16(pA0r0, d);                         \
    load_lds16(pA0r1, d + 8192);                  \
    pA0r0 += 64;                                  \
    pA0r1 += 64;                                  \
  }
#define GUST_A1(PAR)                              \
  {                                               \
    char* d = stA + (PAR) * 32768 + 16384;        \
    load_lds16(pA1r0, d);                         \
    load_lds16(pA1r1, d + 8192);                  \
    pA1r0 += 64;                                  \
    pA1r1 += 64;                                  \
  }
#define GUST_B0(PAR)                              \
  {                                               \
    char* d = stB + (PAR) * 32768;                \
    load_lds16(pB0r0, d);                         \
    load_lds16(pB0r1, d + 8192);                  \
    pB0r0 += 64;                                  \
    pB0r1 += 64;                                  \
  }
#define GUST_B1(PAR)                              \
  {                                               \
    char* d = stB + (PAR) * 32768 + 16384;        \
    load_lds16(pB1r0, d);                         \
    load_lds16(pB1r1, d + 8192);                  \
    pB1r0 += 64;                                  \
    pB1r1 += 64;                                  \
  }

#define GUDSR(P, OFF) (*(const bf16x8*)((P) + (OFF)))

#define GUMM(MB)                                              \
  acc[(MB) + 0][0] = mfma_bf16(a0, b0, acc[(MB) + 0][0]);     \
  acc[(MB) + 0][1] = mfma_bf16(a0, b1, acc[(MB) + 0][1]);     \
  acc[(MB) + 0][2] = mfma_bf16(a0, b2, acc[(MB) + 0][2]);     \
  acc[(MB) + 0][3] = mfma_bf16(a0, b3, acc[(MB) + 0][3]);     \
  acc[(MB) + 1][0] = mfma_bf16(a1, b0, acc[(MB) + 1][0]);     \
  acc[(MB) + 1][1] = mfma_bf16(a1, b1, acc[(MB) + 1][1]);     \
  acc[(MB) + 1][2] = mfma_bf16(a1, b2, acc[(MB) + 1][2]);     \
  acc[(MB) + 1][3] = mfma_bf16(a1, b3, acc[(MB) + 1][3]);     \
  acc[(MB) + 2][0] = mfma_bf16(a2, b0, acc[(MB) + 2][0]);     \
  acc[(MB) + 2][1] = mfma_bf16(a2, b1, acc[(MB) + 2][1]);     \
  acc[(MB) + 2][2] = mfma_bf16(a2, b2, acc[(MB) + 2][2]);     \
  acc[(MB) + 2][3] = mfma_bf16(a2, b3, acc[(MB) + 2][3]);     \
  acc[(MB) + 3][0] = mfma_bf16(a3, b0, acc[(MB) + 3][0]);     \
  acc[(MB) + 3][1] = mfma_bf16(a3, b1, acc[(MB) + 3][1]);     \
  acc[(MB) + 3][2] = mfma_bf16(a3, b2, acc[(MB) + 3][2]);     \
  acc[(MB) + 3][3] = mfma_bf16(a3, b3, acc[(MB) + 3][3]);

#define GUTILE(PAR, ST1, ST2, VM2, ST3, ST4, VM4)                     \
  {                                                                   \
    const char* bApt = rdA + (PAR) * 32768;                           \
    const char* bBpt = rdB + (PAR) * 32768;                           \
    bf16x8 a0, a1, a2, a3, b0, b1, b2, b3;                            \
    /* ph1: kk0, m0-3 */                                              \
    b0 = GUDSR(bBpt, 0);                                              \
    b1 = GUDSR(bBpt, 1024);                                           \
    b2 = GUDSR(bBpt, 2048);                                           \
    b3 = GUDSR(bBpt, 3072);                                           \
    a0 = GUDSR(bApt, 0);                                              \
    a1 = GUDSR(bApt, 1024);                                           \
    a2 = GUDSR(bApt, 2048);                                           \
    a3 = GUDSR(bApt, 3072);                                           \
    ST1;                                                              \
    __builtin_amdgcn_s_barrier();                                     \
    __builtin_amdgcn_s_setprio(1);                                    \
    GUMM(0);                                                          \
    __builtin_amdgcn_s_setprio(0);                                    \
    __builtin_amdgcn_s_barrier();                                     \
    /* ph2: kk0, m4-7 (B kk0 reused from regs) */                     \
    a0 = GUDSR(bApt, 4096);                                           \
    a1 = GUDSR(bApt, 5120);                                           \
    a2 = GUDSR(bApt, 6144);                                           \
    a3 = GUDSR(bApt, 7168);                                           \
    ST2;                                                              \
    VM2;                                                              \
    __builtin_amdgcn_s_barrier();                                     \
    __builtin_amdgcn_s_setprio(1);                                    \
    GUMM(4);                                                          \
    __builtin_amdgcn_s_setprio(0);                                    \
    __builtin_amdgcn_s_barrier();                                     \
    /* ph3: kk1, m0-3 */                                              \
    b0 = GUDSR(bBpt, 16384);                                          \
    b1 = GUDSR(bBpt, 17408);                                          \
    b2 = GUDSR(bBpt, 18432);                                          \
    b3 = GUDSR(bBpt, 19456);                                          \
    a0 = GUDSR(bApt, 16384);                                          \
    a1 = GUDSR(bApt, 17408);                                          \
    a2 = GUDSR(bApt, 18432);                                          \
    a3 = GUDSR(bApt, 19456);                                          \
    ST3;                                                              \
    __builtin_amdgcn_s_barrier();                                     \
    __builtin_amdgcn_s_setprio(1);                                    \
    GUMM(0);                                                          \
    __builtin_amdgcn_s_setprio(0);                                    \
    __builtin_amdgcn_s_barrier();                                     \
    /* ph4: kk1, m4-7 */                                              \
    a0 = GUDSR(bApt, 20480);                                          \
    a1 = GUDSR(bApt, 21504);                                          \
    a2 = GUDSR(bApt, 22528);                                          \
    a3 = GUDSR(bApt, 23552);                                          \
    ST4;                                                              \
    VM4;                                                              \
    __builtin_amdgcn_s_barrier();                                     \
    __builtin_amdgcn_s_setprio(1);                                    \
    GUMM(4);                                                          \
    __builtin_amdgcn_s_setprio(0);                                    \
    __builtin_amdgcn_s_barrier();                                     \
  }

__global__ __launch_bounds__(512, 2) void k_gu(
    const __bf16* __restrict__ xb, const __bf16* __restrict__ Wfu,
    const int* __restrict__ tok, const float* __restrict__ wtl,
    const int* __restrict__ cnt, __bf16* __restrict__ inter) {
  const int e = blockIdx.z;
  const bool se = (e == 8);
  const int cnt_e = se ? T_TOTAL : cnt[e * CNT_STRIDE];
  const int m0 = blockIdx.x * 256;
  if (m0 >= cnt_e) return;  // uniform early-exit before any barrier

  __shared__ __align__(16) char ldsA[65536];  // [par][kh] 16KB regions
  __shared__ __align__(16) char ldsB[65536];

  const int tid = threadIdx.x;
  const int w = tid >> 6, lane = tid & 63;
  const int quad = lane >> 4, l16 = lane & 15;
  const int wm = (w & 1) * 128, wn = (w >> 1) * 64;  // 2M x 4N waves
  const int n0 = blockIdx.y * 256;

  // ---- staging source setup: thread covers row (tid>>2) of each rowhalf,
  // 16B chunk cg = (tid&3) ^ ((tid>>3)&3) (source-side swizzle).
  const int srow = tid >> 2;
  const int cg = (tid & 3) ^ ((tid >> 3) & 3);

  int s0 = m0 + srow;
  if (s0 > cnt_e - 1) s0 = cnt_e - 1;
  int s1 = m0 + 128 + srow;
  if (s1 > cnt_e - 1) s1 = cnt_e - 1;
  const int t0 = se ? s0 : tok[e * T_TOTAL + s0];
  const int t1 = se ? s1 : tok[e * T_TOTAL + s1];
  const __bf16* pA0r0 = xb + (size_t)t0 * HDIM + cg * 8;  // (A,kh0) stream
  const __bf16* pA0r1 = xb + (size_t)t1 * HDIM + cg * 8;
  const __bf16* pA1r0 = pA0r0 + 32;                       // (A,kh1) stream
  const __bf16* pA1r1 = pA0r1 + 32;
  const __bf16* pB0r0 =
      Wfu + ((size_t)e * 1024 + n0 + srow) * HDIM + cg * 8;
  const __bf16* pB0r1 =
      Wfu + ((size_t)e * 1024 + n0 + 128 + srow) * HDIM + cg * 8;
  const __bf16* pB1r0 = pB0r0 + 32;
  const __bf16* pB1r1 = pB0r1 + 32;

  char* const stA = ldsA + w * 1024;  // wave-uniform stage dest base
  char* const stB = ldsB + w * 1024;

  // ---- frag read bases: row r at r*64, swizzled chunk = quad ^ ((l16>>1)&3)
  const int so16 = (quad ^ ((l16 >> 1) & 3)) << 4;
  const char* const rdA = ldsA + (wm + l16) * 64 + so16;
  const char* const rdB = ldsB + (wn + l16) * 64 + so16;

  f32x4 acc[8][4];
#pragma unroll
  for (int m = 0; m < 8; m++)
#pragma unroll
    for (int n = 0; n < 4; n++) acc[m][n] = {0.f, 0.f, 0.f, 0.f};

  // ---- prologue: stage k0 (kh0,kh1) + k1 (kh0); oldest-2 done at vmcnt(8)
  GUST_A0(0);
  GUST_B0(0);
  GUST_A1(0);
  GUST_B1(0);
  GUST_A0(1);
  GUST_B0(1);
  VM8A;
  __builtin_amdgcn_s_barrier();

  // ---- main loop: k = 0..13 (even/odd pairs), then peel k=14, k=15
#pragma unroll 1
  for (int kp = 0; kp < 7; ++kp) {
    GUTILE(0, GUST_A1(1), GUST_B1(1), VM8A, GUST_A0(0), GUST_B0(0), VM8A);
    GUTILE(1, GUST_A1(0), GUST_B1(0), VM8A, GUST_A0(1), GUST_B0(1), VM8A);
  }
  GUTILE(0, GUST_A1(1), GUST_B1(1), VM8A, GUNOP, GUNOP, VM4A);
  GUTILE(1, GUNOP, GUNOP, VM0A, GUNOP, GUNOP, GUNOP);

  // ---- epilogue: C/D col=lane&15, row=quad*4+r; G/U pairs in even/odd n-frags
#pragma unroll
  for (int m = 0; m < 8; ++m) {
#pragma unroll
    for (int r = 0; r < 4; ++r) {
      const int slot = m0 + wm + m * 16 + quad * 4 + r;
      if (slot < cnt_e) {
        const float wt = se ? 1.0f : wtl[e * T_TOTAL + slot];
        __bf16* op = inter + ((size_t)e * T_TOTAL + slot) * IDIM +
                     ((n0 + wn) >> 1) + l16;
#pragma unroll
        for (int p = 0; p < 2; ++p) {
          const float g = acc[m][2 * p][r];
          const float u = acc[m][2 * p + 1][r];
          const float v =
              wt * u * 0.5f * g * (1.0f + erff(g * 0.70710678118654752f));
          op[p * 16] = (__bf16)v;
        }
      }
    }
  }
}

// ---------------------------------------------------------------------------
// Phase B shared: out[T][H] = inter[8] @ Wd[8]  (plain stores, runs first)
// ---------------------------------------------------------------------------
__global__ __launch_bounds__(256, 2) void k_down_s(const __bf16* __restrict__ iA,
                                                   const __bf16* __restrict__ wB,
                                                   float* __restrict__ out) {
  __shared__ __bf16 sA[128][64];
  __shared__ __bf16 sB[128][64];
  const int tid = threadIdx.x, w = tid >> 6, lane = tid & 63;
  const int m0 = blockIdx.x * 128, n0 = blockIdx.y * 128;
  const int quad = lane >> 4, l16 = lane & 15;
  const int wm = (w & 1) * 64, wn = (w >> 1) * 64;

  const int sr = tid >> 3;
  const int scs = ((tid & 7) ^ (sr & 7)) * 8;
  const __bf16* ap[4];
  const __bf16* bp[4];
#pragma unroll
  for (int sh = 0; sh < 4; sh++) {
    ap[sh] = iA + (size_t)(m0 + sh * 32 + sr) * IDIM + scs;
    bp[sh] = wB + (size_t)(n0 + sh * 32 + sr) * IDIM + scs;
  }
  char* const la = (char*)sA + w * 1024;
  char* const lb = (char*)sB + w * 1024;

  f32x4 acc[4][4];
#pragma unroll
  for (int im = 0; im < 4; im++)
#pragma unroll
    for (int in = 0; in < 4; in++) acc[im][in] = {0.f, 0.f, 0.f, 0.f};

  for (int k = 0; k < IDIM; k += 64) {
    __syncthreads();
#pragma unroll
    for (int sh = 0; sh < 4; sh++) {
      load_lds16(ap[sh], la + sh * 4096);
      load_lds16(bp[sh], lb + sh * 4096);
      ap[sh] += 64;
      bp[sh] += 64;
    }
    __syncthreads();
#pragma unroll
    for (int kh = 0; kh < 2; kh++) {
      bf16x8 af[4], bfr[4];
#pragma unroll
      for (int i = 0; i < 4; i++) {
        const int ra = wm + i * 16 + l16;
        af[i] = *(const bf16x8*)((const char*)sA + ra * 128 +
                                 ((kh * 4 + quad) ^ (ra & 7)) * 16);
        const int rb = wn + i * 16 + l16;
        bfr[i] = *(const bf16x8*)((const char*)sB + rb * 128 +
                                  ((kh * 4 + quad) ^ (rb & 7)) * 16);
      }
#pragma unroll
      for (int im = 0; im < 4; im++)
#pragma unroll
        for (int in = 0; in < 4; in++)
          acc[im][in] = mfma_bf16(af[im], bfr[in], acc[im][in]);
    }
  }

#pragma unroll
  for (int im = 0; im < 4; im++) {
#pragma unroll
    for (int r = 0; r < 4; r++) {
      const int t = m0 + wm + im * 16 + quad * 4 + r;
#pragma unroll
      for (int in = 0; in < 4; in++)
        out[(size_t)t * HDIM + n0 + wn + in * 16 + l16] = acc[im][in][r];
    }
  }
}

// ---------------------------------------------------------------------------
// Phase B routed: per expert e, gathered GEMM inter[e][0..cnt) @ Wd[e],
// atomic scatter-add into out (after k_down_s initialized it).
// ---------------------------------------------------------------------------
__global__ __launch_bounds__(256, 2) void k_down_r(
    const __bf16* __restrict__ inter, const __bf16* __restrict__ WdT,
    const int* __restrict__ tok, const int* __restrict__ cnt,
    float* __restrict__ out) {
  const int e = blockIdx.z;
  const int cnt_e = cnt[e * CNT_STRIDE];
  const int m0 = blockIdx.x * 128;
  if (m0 >= cnt_e) return;

  __shared__ __bf16 sA[128][64];
  __shared__ __bf16 sB[128][64];
  const int tid = threadIdx.x, w = tid >> 6, lane = tid & 63;
  const int n0 = blockIdx.y * 128;
  const int quad = lane >> 4, l16 = lane & 15;
  const int wm = (w & 1) * 64, wn = (w >> 1) * 64;

  const int sr = tid >> 3;
  const int scs = ((tid & 7) ^ (sr & 7)) * 8;
  const __bf16* ap[4];
  const __bf16* bp[4];
#pragma unroll
  for (int sh = 0; sh < 4; sh++) {
    int s = m0 + sh * 32 + sr;
    if (s > cnt_e - 1) s = cnt_e - 1;
    ap[sh] = inter + ((size_t)e * T_TOTAL + s) * IDIM + scs;
    bp[sh] = WdT + ((size_t)e * HDIM + n0 + sh * 32 + sr) * IDIM + scs;
  }
  char* const la = (char*)sA + w * 1024;
  char* const lb = (char*)sB + w * 1024;

  f32x4 acc[4][4];
#pragma unroll
  for (int im = 0; im < 4; im++)
#pragma unroll
    for (int in = 0; in < 4; in++) acc[im][in] = {0.f, 0.f, 0.f, 0.f};

  for (int k = 0; k < IDIM; k += 64) {
    __syncthreads();
#pragma unroll
    for (int sh = 0; sh < 4; sh++) {
      load_lds16(ap[sh], la + sh * 4096);
      load_lds16(bp[sh], lb + sh * 4096);
      ap[sh] += 64;
      bp[sh] += 64;
    }
    __syncthreads();
#pragma unroll
    for (int kh = 0; kh < 2; kh++) {
      bf16x8 af[4], bfr[4];
#pragma unroll
      for (int i = 0; i < 4; i++) {
        const int ra = wm + i * 16 + l16;
        af[i] = *(const bf16x8*)((const char*)sA + ra * 128 +
                                 ((kh * 4 + quad) ^ (ra & 7)) * 16);
        const int rb = wn + i * 16 + l16;
        bfr[i] = *(const bf16x8*)((const char*)sB + rb * 128 +
                                  ((kh * 4 + quad) ^ (rb & 7)) * 16);
      }
#pragma unroll
      for (int im = 0; im < 4; im++)
#pragma unroll
        for (int in = 0; in < 4; in++)
          acc[im][in] = mfma_bf16(af[im], bfr[in], acc[im][in]);
    }
  }

#pragma unroll
  for (int im = 0; im < 4; im++) {
#pragma unroll
    for (int r = 0; r < 4; r++) {
      const int slot = m0 + wm + im * 16 + quad * 4 + r;
      if (slot < cnt_e) {
        const int t = tok[e * T_TOTAL + slot];
#pragma unroll
        for (int in = 0; in < 4; in++)
          atomicAdd(&out[(size_t)t * HDIM + n0 + wn + in * 16 + l16],
                    acc[im][in][r]);
      }
    }
  }
}

// ---------------------------------------------------------------------------
extern "C" void kernel_launch(void* const* d_in, const int* in_sizes, int n_in,
                              void* d_out, int out_size, void* d_ws,
                              size_t ws_size, hipStream_t stream) {
  const float* x = (const float*)d_in[0];
  const float* gw = (const float*)d_in[1];
  const float* Wg = (const float*)d_in[2];
  const float* Wu = (const float*)d_in[3];
  const float* Wd = (const float*)d_in[4];
  const float* sWg = (const float*)d_in[5];
  const float* sWu = (const float*)d_in[6];
  const float* sWd = (const float*)d_in[7];
  float* out = (float*)d_out;

  char* ws = (char*)d_ws;
  size_t off = 0;
  auto alloc = [&](size_t n) {
    char* p = ws + off;
    off += (n + 255) & ~(size_t)255;
    return p;
  };
  __bf16* xb = (__bf16*)alloc((size_t)T_TOTAL * HDIM * 2);          // 33.5 MB
  __bf16* Wfu = (__bf16*)alloc((size_t)NE * 1024 * HDIM * 2);       // 18.9 MB
  __bf16* WdT = (__bf16*)alloc((size_t)NE * HDIM * IDIM * 2);       // 9.4 MB
  int* tok = (int*)alloc((size_t)8 * T_TOTAL * 4);                  // 512 KB
  float* wtl = (float*)alloc((size_t)8 * T_TOTAL * 4);              // 512 KB
  int* cnt = (int*)alloc(8 * CNT_STRIDE * 4);
  __bf16* inter = (__bf16*)alloc((size_t)NE * T_TOTAL * IDIM * 2);  // 151 MB

  hipMemsetAsync(cnt, 0, 8 * CNT_STRIDE * 4, stream);

  k_gate<<<dim3(T_TOTAL / 64), dim3(256), 0, stream>>>(x, gw, xb, tok, wtl,
                                                       cnt);
  // Wg/sWg -> fused rows +0 (G), Wu/sWu -> fused rows +16 (U)
  k_transpose_fuse<<<dim3(IDIM / 32, HDIM / 32, NE), dim3(256), 0, stream>>>(
      Wg, sWg, Wfu, 0);
  k_transpose_fuse<<<dim3(IDIM / 32, HDIM / 32, NE), dim3(256), 0, stream>>>(
      Wu, sWu, Wfu, 16);
  // Wd [8][I][H] + sWd [I][H] -> WdT [9][H][I]
  k_transpose<<<dim3(HDIM / 32, IDIM / 32, NE), dim3(256), 0, stream>>>(
      Wd, sWd, WdT, IDIM, HDIM);

  // Phase A: fused GU, 256x256 tiles, 8 waves; worst-case x grid, early-exit.
  k_gu<<<dim3(T_TOTAL / 256, 1024 / 256, NE), dim3(512), 0, stream>>>(
      xb, Wfu, tok, wtl, cnt, inter);

  // Phase B: shared expert first (plain stores initialize out) ...
  k_down_s<<<dim3(T_TOTAL / 128, HDIM / 128), dim3(256), 0, stream>>>(
      inter + (size_t)8 * T_TOTAL * IDIM, WdT + (size_t)8 * HDIM * IDIM, out);
  // ... then routed experts atomic-add on top.
  k_down_r<<<dim3(T_TOTAL / 128, HDIM / 128, 8), dim3(256), 0, stream>>>(
      inter, WdT, tok, cnt, out);
}

// Round 3
// 501.034 us; speedup vs baseline: 1.1386x; 1.1022x over previous
//
#include <hip/hip_runtime.h>
#include <hip/hip_bf16.h>
#include <math.h>

// ---------------------------------------------------------------------------
// DeepseekV2 MoE: T=16384 tokens, H=1024, E=8 routed (top-2) + 1 shared, I=512
// Round 7:
//  - k_gu REVERTED to round-4 structure (128x128, 4 waves, 2 blocks/CU,
//    simple 2-barrier K-loop): 141us / 730TF proven. Rounds 5-6 phased
//    schedules (219/283us) both regressed: barrier-lockstep at 1 block/CU
//    exposes LDS latency with no co-resident work (m232 open quadrant).
//  - k_down_r atomics removed: dense stores into packed ybuf fp32
//    (row = scan(cnt)[e] + slot), then k_combine gathers each token's two
//    routed rows via inv[] map from k_gate: out[t] += y1 + y2.
//    134M scattered 4B atomicAdds -> coalesced float4 streams.
//  - Host-side fallback to atomic path if ws_size can't fit ybuf (+134MB).
// ---------------------------------------------------------------------------

#define T_TOTAL 16384
#define HDIM 1024
#define IDIM 512
#define NE 9  // 8 routed + 1 shared (expert index 8)
#define CNT_STRIDE 16

typedef __bf16 bf16x8 __attribute__((ext_vector_type(8)));
typedef float f32x4 __attribute__((ext_vector_type(4)));

typedef __attribute__((address_space(1))) void gvoid_t;
typedef __attribute__((address_space(3))) void lvoid_t;

__device__ __forceinline__ void load_lds16(const void* g, void* l) {
  // 16B/lane; LDS dest = wave-uniform base + lane*16 (global src may scatter)
  __builtin_amdgcn_global_load_lds((const gvoid_t*)g, (lvoid_t*)l, 16, 0, 0);
}

__device__ __forceinline__ f32x4 mfma_bf16(bf16x8 a, bf16x8 b, f32x4 c) {
  return __builtin_amdgcn_mfma_f32_16x16x32_bf16(a, b, c, 0, 0, 0);
}

// ---------------------------------------------------------------------------
// Gate: block-aggregated slot assignment. Also writes inv[t*2+j] = e*16384+slot
// (T_TOTAL = 2^14 -> decode e = v>>14, slot = v&16383).
// ---------------------------------------------------------------------------
__global__ __launch_bounds__(256) void k_gate(const float* __restrict__ x,
                                              const float* __restrict__ gw,
                                              __bf16* __restrict__ xb,
                                              int* __restrict__ tok,
                                              float* __restrict__ wtl,
                                              int* __restrict__ cnt,
                                              int* __restrict__ inv) {
  __shared__ int s_eid[64][2];
  __shared__ float s_wt[64][2];
  __shared__ int s_rank[64][2];
  __shared__ int lcnt[8];
  __shared__ int lbase[8];
  const int wv = threadIdx.x >> 6, lane = threadIdx.x & 63;
  if (threadIdx.x < 8) lcnt[threadIdx.x] = 0;
  __syncthreads();

  for (int i = 0; i < 16; i++) {
    const int tl = wv * 16 + i;
    const int t = blockIdx.x * 64 + tl;
    const float* xr = x + (size_t)t * HDIM + lane * 16;
    float4 xv[4];
#pragma unroll
    for (int j = 0; j < 4; j++) xv[j] = ((const float4*)xr)[j];

    bf16x8 v0, v1;
#pragma unroll
    for (int j = 0; j < 8; j++) v0[j] = (__bf16)((const float*)xv)[j];
#pragma unroll
    for (int j = 0; j < 8; j++) v1[j] = (__bf16)((const float*)xv)[j + 8];
    bf16x8* xbo = (bf16x8*)(xb + (size_t)t * HDIM + lane * 16);
    xbo[0] = v0;
    xbo[1] = v1;

    float acc[8];
#pragma unroll
    for (int e = 0; e < 8; e++) {
      const float4* gp = (const float4*)(gw + e * HDIM + lane * 16);
      float s = 0.f;
#pragma unroll
      for (int j = 0; j < 4; j++) {
        float4 g = gp[j];
        s += xv[j].x * g.x + xv[j].y * g.y + xv[j].z * g.z + xv[j].w * g.w;
      }
      acc[e] = s;
    }
#pragma unroll
    for (int d = 32; d >= 1; d >>= 1) {
#pragma unroll
      for (int e = 0; e < 8; e++) acc[e] += __shfl_xor(acc[e], d, 64);
    }
    if (lane == 0) {
      float mx = acc[0];
#pragma unroll
      for (int e = 1; e < 8; e++) mx = fmaxf(mx, acc[e]);
      float p[8], Z = 0.f;
#pragma unroll
      for (int e = 0; e < 8; e++) {
        p[e] = expf(acc[e] - mx);
        Z += p[e];
      }
#pragma unroll
      for (int e = 0; e < 8; e++) p[e] /= Z;
      int i1 = 0;
#pragma unroll
      for (int e = 1; e < 8; e++)
        if (p[e] > p[i1]) i1 = e;
      int i2 = (i1 == 0) ? 1 : 0;
#pragma unroll
      for (int e = 0; e < 8; e++)
        if (e != i1 && p[e] > p[i2]) i2 = e;
      const float s12 = p[i1] + p[i2] + 1e-20f;
      s_eid[tl][0] = i1;
      s_eid[tl][1] = i2;
      s_wt[tl][0] = p[i1] / s12;
      s_wt[tl][1] = p[i2] / s12;
    }
  }
  __syncthreads();

  if (threadIdx.x < 64) {
    s_rank[threadIdx.x][0] = atomicAdd(&lcnt[s_eid[threadIdx.x][0]], 1);
    s_rank[threadIdx.x][1] = atomicAdd(&lcnt[s_eid[threadIdx.x][1]], 1);
  }
  __syncthreads();
  if (threadIdx.x < 8)
    lbase[threadIdx.x] =
        atomicAdd(&cnt[threadIdx.x * CNT_STRIDE], lcnt[threadIdx.x]);
  __syncthreads();
  if (threadIdx.x < 64) {
    const int t = blockIdx.x * 64 + threadIdx.x;
#pragma unroll
    for (int j = 0; j < 2; j++) {
      const int e = s_eid[threadIdx.x][j];
      const int slot = lbase[e] + s_rank[threadIdx.x][j];
      tok[e * T_TOTAL + slot] = t;
      wtl[e * T_TOTAL + slot] = s_wt[threadIdx.x][j];
      inv[t * 2 + j] = e * T_TOTAL + slot;
    }
  }
}

// ---------------------------------------------------------------------------
// Exclusive prefix scan of per-expert counts (8 values) -> base[e].
// ---------------------------------------------------------------------------
__global__ void k_scan(const int* __restrict__ cnt, int* __restrict__ base) {
  if (threadIdx.x == 0 && blockIdx.x == 0) {
    int s = 0;
#pragma unroll
    for (int e = 0; e < 8; e++) {
      base[e] = s;
      s += cnt[e * CNT_STRIDE];
    }
  }
}

// ---------------------------------------------------------------------------
// Plain transpose+cast (for Wd): src fp32 [R][C] -> out bf16 [b][C][R]
// ---------------------------------------------------------------------------
__global__ __launch_bounds__(256) void k_transpose(const float* __restrict__ w8,
                                                   const float* __restrict__ w1,
                                                   __bf16* __restrict__ out,
                                                   int R, int C) {
  __shared__ float tile[32][33];
  const int b = blockIdx.z;
  const float* src = (b < 8) ? (w8 + (size_t)b * R * C) : w1;
  const int c0 = blockIdx.x * 32, r0 = blockIdx.y * 32;
  const int tx = threadIdx.x & 31, ty = threadIdx.x >> 5;
#pragma unroll
  for (int i = 0; i < 4; i++)
    tile[ty + i * 8][tx] = src[(size_t)(r0 + ty + i * 8) * C + c0 + tx];
  __syncthreads();
#pragma unroll
  for (int i = 0; i < 4; i++)
    out[(size_t)b * R * C + (size_t)(c0 + ty + i * 8) * R + r0 + tx] =
        (__bf16)tile[tx][ty + i * 8];
}

// ---------------------------------------------------------------------------
// Fused-GU transpose: src fp32 [b][1024 h][512 i] -> Wfu bf16 [b][1024 f][1024 h]
// fused row f(i) = 2*(i & ~15) + (i & 15) + u16off  (u16off: 0 for G, 16 for U)
// ---------------------------------------------------------------------------
__global__ __launch_bounds__(256) void k_transpose_fuse(
    const float* __restrict__ w8, const float* __restrict__ w1,
    __bf16* __restrict__ out, int u16off) {
  __shared__ float tile[32][33];
  const int b = blockIdx.z;
  const float* src = (b < 8) ? (w8 + (size_t)b * HDIM * IDIM) : w1;
  const int c0 = blockIdx.x * 32, r0 = blockIdx.y * 32;  // c=i, r=h
  const int tx = threadIdx.x & 31, ty = threadIdx.x >> 5;
#pragma unroll
  for (int i = 0; i < 4; i++)
    tile[ty + i * 8][tx] = src[(size_t)(r0 + ty + i * 8) * IDIM + c0 + tx];
  __syncthreads();
#pragma unroll
  for (int i = 0; i < 4; i++) {
    const int ic = c0 + ty + i * 8;
    const int f = 2 * (ic & ~15) + (ic & 15) + u16off;
    out[(size_t)b * 1024 * HDIM + (size_t)f * HDIM + r0 + tx] =
        (__bf16)tile[tx][ty + i * 8];
  }
}

// ---------------------------------------------------------------------------
// Phase A (round-4 state): one GEMM [slots x 128 fused cols], K=H.
// acc[im][2p]=G, acc[im][2p+1]=U for i-col = (n0+wn)/2 + p*16 + l16.
// BK=64, XOR-swizzled LDS, 2 staging streams.
// ---------------------------------------------------------------------------
__global__ __launch_bounds__(256, 2) void k_gu(
    const __bf16* __restrict__ xb, const __bf16* __restrict__ Wfu,
    const int* __restrict__ tok, const float* __restrict__ wtl,
    const int* __restrict__ cnt, __bf16* __restrict__ inter) {
  const int e = blockIdx.z;
  const bool se = (e == 8);
  const int cnt_e = se ? T_TOTAL : cnt[e * CNT_STRIDE];
  const int m0 = blockIdx.x * 128;
  if (m0 >= cnt_e) return;  // uniform early-exit before any barrier

  __shared__ __bf16 sA[128][64];
  __shared__ __bf16 sB[128][64];
  const int tid = threadIdx.x, w = tid >> 6, lane = tid & 63;
  const int n0 = blockIdx.y * 128;  // fused-row base (0..896)
  const int quad = lane >> 4, l16 = lane & 15;
  const int wm = (w & 1) * 64, wn = (w >> 1) * 64;

  // staging: 256 thr x 16B = 4KB/shot = 32 rows of 128B; 4 shots per buffer
  const int sr = tid >> 3;                     // row within shot
  const int scs = ((tid & 7) ^ (sr & 7)) * 8;  // swizzled source offset (elems)
  const __bf16* ap[4];
  const __bf16* bp[4];
#pragma unroll
  for (int sh = 0; sh < 4; sh++) {
    int s = m0 + sh * 32 + sr;
    if (s > cnt_e - 1) s = cnt_e - 1;
    const int t = se ? s : tok[e * T_TOTAL + s];
    ap[sh] = xb + (size_t)t * HDIM + scs;
    bp[sh] = Wfu + ((size_t)e * 1024 + n0 + sh * 32 + sr) * HDIM + scs;
  }
  char* const la = (char*)sA + w * 1024;  // +lane*16 implicit in global_load_lds
  char* const lb = (char*)sB + w * 1024;

  f32x4 acc[4][4];
#pragma unroll
  for (int im = 0; im < 4; im++)
#pragma unroll
    for (int in = 0; in < 4; in++) acc[im][in] = {0.f, 0.f, 0.f, 0.f};

  for (int k = 0; k < HDIM; k += 64) {
    __syncthreads();
#pragma unroll
    for (int sh = 0; sh < 4; sh++) {
      load_lds16(ap[sh], la + sh * 4096);
      load_lds16(bp[sh], lb + sh * 4096);
      ap[sh] += 64;
      bp[sh] += 64;
    }
    __syncthreads();
#pragma unroll
    for (int kh = 0; kh < 2; kh++) {
      bf16x8 af[4], bfr[4];
#pragma unroll
      for (int i = 0; i < 4; i++) {
        const int ra = wm + i * 16 + l16;
        af[i] = *(const bf16x8*)((const char*)sA + ra * 128 +
                                 ((kh * 4 + quad) ^ (ra & 7)) * 16);
        const int rb = wn + i * 16 + l16;
        bfr[i] = *(const bf16x8*)((const char*)sB + rb * 128 +
                                  ((kh * 4 + quad) ^ (rb & 7)) * 16);
      }
#pragma unroll
      for (int im = 0; im < 4; im++)
#pragma unroll
        for (int in = 0; in < 4; in++)
          acc[im][in] = mfma_bf16(af[im], bfr[in], acc[im][in]);
    }
  }

  // epilogue: C/D col=lane&15, row=quad*4+r; G/U pairs in even/odd n-frags
#pragma unroll
  for (int im = 0; im < 4; im++) {
#pragma unroll
    for (int r = 0; r < 4; r++) {
      const int slot = m0 + wm + im * 16 + quad * 4 + r;
      if (slot < cnt_e) {
        const float wt = se ? 1.0f : wtl[e * T_TOTAL + slot];
        __bf16* op =
            inter + ((size_t)e * T_TOTAL + slot) * IDIM + ((n0 + wn) >> 1) + l16;
#pragma unroll
        for (int p = 0; p < 2; p++) {
          const float g = acc[im][2 * p][r];
          const float u = acc[im][2 * p + 1][r];
          const float v =
              wt * u * 0.5f * g * (1.0f + erff(g * 0.70710678118654752f));
          op[p * 16] = (__bf16)v;
        }
      }
    }
  }
}

// ---------------------------------------------------------------------------
// Phase B shared: out[T][H] = inter[8] @ Wd[8]  (plain stores, runs first)
// ---------------------------------------------------------------------------
__global__ __launch_bounds__(256, 2) void k_down_s(const __bf16* __restrict__ iA,
                                                   const __bf16* __restrict__ wB,
                                                   float* __restrict__ out) {
  __shared__ __bf16 sA[128][64];
  __shared__ __bf16 sB[128][64];
  const int tid = threadIdx.x, w = tid >> 6, lane = tid & 63;
  const int m0 = blockIdx.x * 128, n0 = blockIdx.y * 128;
  const int quad = lane >> 4, l16 = lane & 15;
  const int wm = (w & 1) * 64, wn = (w >> 1) * 64;

  const int sr = tid >> 3;
  const int scs = ((tid & 7) ^ (sr & 7)) * 8;
  const __bf16* ap[4];
  const __bf16* bp[4];
#pragma unroll
  for (int sh = 0; sh < 4; sh++) {
    ap[sh] = iA + (size_t)(m0 + sh * 32 + sr) * IDIM + scs;
    bp[sh] = wB + (size_t)(n0 + sh * 32 + sr) * IDIM + scs;
  }
  char* const la = (char*)sA + w * 1024;
  char* const lb = (char*)sB + w * 1024;

  f32x4 acc[4][4];
#pragma unroll
  for (int im = 0; im < 4; im++)
#pragma unroll
    for (int in = 0; in < 4; in++) acc[im][in] = {0.f, 0.f, 0.f, 0.f};

  for (int k = 0; k < IDIM; k += 64) {
    __syncthreads();
#pragma unroll
    for (int sh = 0; sh < 4; sh++) {
      load_lds16(ap[sh], la + sh * 4096);
      load_lds16(bp[sh], lb + sh * 4096);
      ap[sh] += 64;
      bp[sh] += 64;
    }
    __syncthreads();
#pragma unroll
    for (int kh = 0; kh < 2; kh++) {
      bf16x8 af[4], bfr[4];
#pragma unroll
      for (int i = 0; i < 4; i++) {
        const int ra = wm + i * 16 + l16;
        af[i] = *(const bf16x8*)((const char*)sA + ra * 128 +
                                 ((kh * 4 + quad) ^ (ra & 7)) * 16);
        const int rb = wn + i * 16 + l16;
        bfr[i] = *(const bf16x8*)((const char*)sB + rb * 128 +
                                  ((kh * 4 + quad) ^ (rb & 7)) * 16);
      }
#pragma unroll
      for (int im = 0; im < 4; im++)
#pragma unroll
        for (int in = 0; in < 4; in++)
          acc[im][in] = mfma_bf16(af[im], bfr[in], acc[im][in]);
    }
  }

#pragma unroll
  for (int im = 0; im < 4; im++) {
#pragma unroll
    for (int r = 0; r < 4; r++) {
      const int t = m0 + wm + im * 16 + quad * 4 + r;
#pragma unroll
      for (int in = 0; in < 4; in++)
        out[(size_t)t * HDIM + n0 + wn + in * 16 + l16] = acc[im][in][r];
    }
  }
}

// ---------------------------------------------------------------------------
// Phase B routed, STORE version: per expert e, gathered GEMM
// inter[e][0..cnt) @ Wd[e] -> dense fp32 rows yb[base[e]+slot][H]. No atomics.
// ---------------------------------------------------------------------------
__global__ __launch_bounds__(256, 2) void k_down_rs(
    const __bf16* __restrict__ inter, const __bf16* __restrict__ WdT,
    const int* __restrict__ cnt, const int* __restrict__ base,
    float* __restrict__ yb) {
  const int e = blockIdx.z;
  const int cnt_e = cnt[e * CNT_STRIDE];
  const int m0 = blockIdx.x * 128;
  if (m0 >= cnt_e) return;
  const int rowb = base[e];

  __shared__ __bf16 sA[128][64];
  __shared__ __bf16 sB[128][64];
  const int tid = threadIdx.x, w = tid >> 6, lane = tid & 63;
  const int n0 = blockIdx.y * 128;
  const int quad = lane >> 4, l16 = lane & 15;
  const int wm = (w & 1) * 64, wn = (w >> 1) * 64;

  const int sr = tid >> 3;
  const int scs = ((tid & 7) ^ (sr & 7)) * 8;
  const __bf16* ap[4];
  const __bf16* bp[4];
#pragma unroll
  for (int sh = 0; sh < 4; sh++) {
    int s = m0 + sh * 32 + sr;
    if (s > cnt_e - 1) s = cnt_e - 1;
    ap[sh] = inter + ((size_t)e * T_TOTAL + s) * IDIM + scs;
    bp[sh] = WdT + ((size_t)e * HDIM + n0 + sh * 32 + sr) * IDIM + scs;
  }
  char* const la = (char*)sA + w * 1024;
  char* const lb = (char*)sB + w * 1024;

  f32x4 acc[4][4];
#pragma unroll
  for (int im = 0; im < 4; im++)
#pragma unroll
    for (int in = 0; in < 4; in++) acc[im][in] = {0.f, 0.f, 0.f, 0.f};

  for (int k = 0; k < IDIM; k += 64) {
    __syncthreads();
#pragma unroll
    for (int sh = 0; sh < 4; sh++) {
      load_lds16(ap[sh], la + sh * 4096);
      load_lds16(bp[sh], lb + sh * 4096);
      ap[sh] += 64;
      bp[sh] += 64;
    }
    __syncthreads();
#pragma unroll
    for (int kh = 0; kh < 2; kh++) {
      bf16x8 af[4], bfr[4];
#pragma unroll
      for (int i = 0; i < 4; i++) {
        const int ra = wm + i * 16 + l16;
        af[i] = *(const bf16x8*)((const char*)sA + ra * 128 +
                                 ((kh * 4 + quad) ^ (ra & 7)) * 16);
        const int rb = wn + i * 16 + l16;
        bfr[i] = *(const bf16x8*)((const char*)sB + rb * 128 +
                                  ((kh * 4 + quad) ^ (rb & 7)) * 16);
      }
#pragma unroll
      for (int im = 0; im < 4; im++)
#pragma unroll
        for (int in = 0; in < 4; in++)
          acc[im][in] = mfma_bf16(af[im], bfr[in], acc[im][in]);
    }
  }

#pragma unroll
  for (int im = 0; im < 4; im++) {
#pragma unroll
    for (int r = 0; r < 4; r++) {
      const int slot = m0 + wm + im * 16 + quad * 4 + r;
      if (slot < cnt_e) {
        float* op = yb + (size_t)(rowb + slot) * HDIM + n0 + wn + l16;
#pragma unroll
        for (int in = 0; in < 4; in++) op[in * 16] = acc[im][in][r];
      }
    }
  }
}

// ---------------------------------------------------------------------------
// Combine: out[t] += yb[row(inv[2t])] + yb[row(inv[2t+1])]. 1 wave per token,
// coalesced float4 streams. out already holds the shared-expert result.
// ---------------------------------------------------------------------------
__global__ __launch_bounds__(256) void k_combine(const float* __restrict__ yb,
                                                 const int* __restrict__ inv,
                                                 const int* __restrict__ base,
                                                 float* __restrict__ out) {
  const int t = blockIdx.x * 4 + (threadIdx.x >> 6);
  const int lane = threadIdx.x & 63;
  const int v1 = inv[2 * t], v2 = inv[2 * t + 1];
  const int r1 = base[v1 >> 14] + (v1 & (T_TOTAL - 1));
  const int r2 = base[v2 >> 14] + (v2 & (T_TOTAL - 1));
  const float4* y1 = (const float4*)(yb + (size_t)r1 * HDIM);
  const float4* y2 = (const float4*)(yb + (size_t)r2 * HDIM);
  float4* o = (float4*)(out + (size_t)t * HDIM);
#pragma unroll
  for (int j = 0; j < 4; j++) {
    const int c = lane + j * 64;
    float4 a = o[c];
    float4 b = y1[c];
    float4 d = y2[c];
    o[c] = make_float4(a.x + b.x + d.x, a.y + b.y + d.y, a.z + b.z + d.z,
                       a.w + b.w + d.w);
  }
}

// ---------------------------------------------------------------------------
// Phase B routed, ATOMIC fallback (round-4 behavior) if ws can't fit yb.
// ---------------------------------------------------------------------------
__global__ __launch_bounds__(256, 2) void k_down_r(
    const __bf16* __restrict__ inter, const __bf16* __restrict__ WdT,
    const int* __restrict__ tok, const int* __restrict__ cnt,
    float* __restrict__ out) {
  const int e = blockIdx.z;
  const int cnt_e = cnt[e * CNT_STRIDE];
  const int m0 = blockIdx.x * 128;
  if (m0 >= cnt_e) return;

  __shared__ __bf16 sA[128][64];
  __shared__ __bf16 sB[128][64];
  const int tid = threadIdx.x, w = tid >> 6, lane = tid & 63;
  const int n0 = blockIdx.y * 128;
  const int quad = lane >> 4, l16 = lane & 15;
  const int wm = (w & 1) * 64, wn = (w >> 1) * 64;

  const int sr = tid >> 3;
  const int scs = ((tid & 7) ^ (sr & 7)) * 8;
  const __bf16* ap[4];
  const __bf16* bp[4];
#pragma unroll
  for (int sh = 0; sh < 4; sh++) {
    int s = m0 + sh * 32 + sr;
    if (s > cnt_e - 1) s = cnt_e - 1;
    ap[sh] = inter + ((size_t)e * T_TOTAL + s) * IDIM + scs;
    bp[sh] = WdT + ((size_t)e * HDIM + n0 + sh * 32 + sr) * IDIM + scs;
  }
  char* const la = (char*)sA + w * 1024;
  char* const lb = (char*)sB + w * 1024;

  f32x4 acc[4][4];
#pragma unroll
  for (int im = 0; im < 4; im++)
#pragma unroll
    for (int in = 0; in < 4; in++) acc[im][in] = {0.f, 0.f, 0.f, 0.f};

  for (int k = 0; k < IDIM; k += 64) {
    __syncthreads();
#pragma unroll
    for (int sh = 0; sh < 4; sh++) {
      load_lds16(ap[sh], la + sh * 4096);
      load_lds16(bp[sh], lb + sh * 4096);
      ap[sh] += 64;
      bp[sh] += 64;
    }
    __syncthreads();
#pragma unroll
    for (int kh = 0; kh < 2; kh++) {
      bf16x8 af[4], bfr[4];
#pragma unroll
      for (int i = 0; i < 4; i++) {
        const int ra = wm + i * 16 + l16;
        af[i] = *(const bf16x8*)((const char*)sA + ra * 128 +
                                 ((kh * 4 + quad) ^ (ra & 7)) * 16);
        const int rb = wn + i * 16 + l16;
        bfr[i] = *(const bf16x8*)((const char*)sB + rb * 128 +
                                  ((kh * 4 + quad) ^ (rb & 7)) * 16);
      }
#pragma unroll
      for (int im = 0; im < 4; im++)
#pragma unroll
        for (int in = 0; in < 4; in++)
          acc[im][in] = mfma_bf16(af[im], bfr[in], acc[im][in]);
    }
  }

#pragma unroll
  for (int im = 0; im < 4; im++) {
#pragma unroll
    for (int r = 0; r < 4; r++) {
      const int slot = m0 + wm + im * 16 + quad * 4 + r;
      if (slot < cnt_e) {
        const int t = tok[e * T_TOTAL + slot];
#pragma unroll
        for (int in = 0; in < 4; in++)
          atomicAdd(&out[(size_t)t * HDIM + n0 + wn + in * 16 + l16],
                    acc[im][in][r]);
      }
    }
  }
}

// ---------------------------------------------------------------------------
extern "C" void kernel_launch(void* const* d_in, const int* in_sizes, int n_in,
                              void* d_out, int out_size, void* d_ws,
                              size_t ws_size, hipStream_t stream) {
  const float* x = (const float*)d_in[0];
  const float* gw = (const float*)d_in[1];
  const float* Wg = (const float*)d_in[2];
  const float* Wu = (const float*)d_in[3];
  const float* Wd = (const float*)d_in[4];
  const float* sWg = (const float*)d_in[5];
  const float* sWu = (const float*)d_in[6];
  const float* sWd = (const float*)d_in[7];
  float* out = (float*)d_out;

  char* ws = (char*)d_ws;
  size_t off = 0;
  auto alloc = [&](size_t n) {
    char* p = ws + off;
    off += (n + 255) & ~(size_t)255;
    return p;
  };
  __bf16* xb = (__bf16*)alloc((size_t)T_TOTAL * HDIM * 2);          // 33.5 MB
  __bf16* Wfu = (__bf16*)alloc((size_t)NE * 1024 * HDIM * 2);       // 18.9 MB
  __bf16* WdT = (__bf16*)alloc((size_t)NE * HDIM * IDIM * 2);       // 9.4 MB
  int* tok = (int*)alloc((size_t)8 * T_TOTAL * 4);                  // 512 KB
  float* wtl = (float*)alloc((size_t)8 * T_TOTAL * 4);              // 512 KB
  int* cnt = (int*)alloc(8 * CNT_STRIDE * 4);
  int* inv = (int*)alloc((size_t)T_TOTAL * 2 * 4);                  // 128 KB
  int* base = (int*)alloc(16 * 4);
  __bf16* inter = (__bf16*)alloc((size_t)NE * T_TOTAL * IDIM * 2);  // 151 MB

  // Packed routed down-proj output: 2*T rows x H fp32 = 134 MB (optional).
  const size_t yb_bytes = (size_t)2 * T_TOTAL * HDIM * 4;
  const bool store_path = (off + yb_bytes) <= ws_size;
  float* yb = store_path ? (float*)alloc(yb_bytes) : nullptr;

  hipMemsetAsync(cnt, 0, 8 * CNT_STRIDE * 4, stream);

  k_gate<<<dim3(T_TOTAL / 64), dim3(256), 0, stream>>>(x, gw, xb, tok, wtl,
                                                       cnt, inv);
  // Wg/sWg -> fused rows +0 (G), Wu/sWu -> fused rows +16 (U)
  k_transpose_fuse<<<dim3(IDIM / 32, HDIM / 32, NE), dim3(256), 0, stream>>>(
      Wg, sWg, Wfu, 0);
  k_transpose_fuse<<<dim3(IDIM / 32, HDIM / 32, NE), dim3(256), 0, stream>>>(
      Wu, sWu, Wfu, 16);
  // Wd [8][I][H] + sWd [I][H] -> WdT [9][H][I]
  k_transpose<<<dim3(HDIM / 32, IDIM / 32, NE), dim3(256), 0, stream>>>(
      Wd, sWd, WdT, IDIM, HDIM);
  k_scan<<<dim3(1), dim3(64), 0, stream>>>(cnt, base);

  // Phase A: fused GU; worst-case x grid, early-exit.
  k_gu<<<dim3(T_TOTAL / 128, 1024 / 128, NE), dim3(256), 0, stream>>>(
      xb, Wfu, tok, wtl, cnt, inter);

  // Phase B: shared expert (plain stores initialize out) ...
  k_down_s<<<dim3(T_TOTAL / 128, HDIM / 128), dim3(256), 0, stream>>>(
      inter + (size_t)8 * T_TOTAL * IDIM, WdT + (size_t)8 * HDIM * IDIM, out);

  if (store_path) {
    // ... routed experts -> packed yb (no atomics), then gather-combine.
    k_down_rs<<<dim3(T_TOTAL / 128, HDIM / 128, 8), dim3(256), 0, stream>>>(
        inter, WdT, cnt, base, yb);
    k_combine<<<dim3(T_TOTAL / 4), dim3(256), 0, stream>>>(yb, inv, base, out);
  } else {
    // fallback: atomic scatter-add (round-4 behavior)
    k_down_r<<<dim3(T_TOTAL / 128, HDIM / 128, 8), dim3(256), 0, stream>>>(
        inter, WdT, tok, cnt, out);
  }
}

// Round 4
// 493.615 us; speedup vs baseline: 1.1557x; 1.0150x over previous
//
#include <hip/hip_runtime.h>
#include <hip/hip_bf16.h>
#include <math.h>

// ---------------------------------------------------------------------------
// DeepseekV2 MoE: T=16384 tokens, H=1024, E=8 routed (top-2) + 1 shared, I=512
// Round 8:
//  - k_gu: round-4 structure (proven 142us), split into routed/shared
//    launches for per-dispatch profiling visibility.
//  - Phase B: k_down_rs (packed routed rows, pure stores) then k_down_sc =
//    shared-expert GEMM whose epilogue gathers the token's two routed rows
//    and writes out = shared + y1 + y2 (no separate combine pass; no atomics).
//  - Transposes: 64x64 tiles, float4 loads, bf16x8 16B/lane stores
//    (128B-contiguous segments) replacing 64B scattered writes.
//  - Atomic fallback retained if ws can't fit yb (+134MB).
// ---------------------------------------------------------------------------

#define T_TOTAL 16384
#define HDIM 1024
#define IDIM 512
#define NE 9  // 8 routed + 1 shared (expert index 8)
#define CNT_STRIDE 16

typedef __bf16 bf16x8 __attribute__((ext_vector_type(8)));
typedef float f32x4 __attribute__((ext_vector_type(4)));

typedef __attribute__((address_space(1))) void gvoid_t;
typedef __attribute__((address_space(3))) void lvoid_t;

__device__ __forceinline__ void load_lds16(const void* g, void* l) {
  // 16B/lane; LDS dest = wave-uniform base + lane*16 (global src may scatter)
  __builtin_amdgcn_global_load_lds((const gvoid_t*)g, (lvoid_t*)l, 16, 0, 0);
}

__device__ __forceinline__ f32x4 mfma_bf16(bf16x8 a, bf16x8 b, f32x4 c) {
  return __builtin_amdgcn_mfma_f32_16x16x32_bf16(a, b, c, 0, 0, 0);
}

// ---------------------------------------------------------------------------
// Gate: block-aggregated slot assignment. Also writes inv[t*2+j] = e*16384+slot
// (T_TOTAL = 2^14 -> decode e = v>>14, slot = v&16383).
// ---------------------------------------------------------------------------
__global__ __launch_bounds__(256) void k_gate(const float* __restrict__ x,
                                              const float* __restrict__ gw,
                                              __bf16* __restrict__ xb,
                                              int* __restrict__ tok,
                                              float* __restrict__ wtl,
                                              int* __restrict__ cnt,
                                              int* __restrict__ inv) {
  __shared__ int s_eid[64][2];
  __shared__ float s_wt[64][2];
  __shared__ int s_rank[64][2];
  __shared__ int lcnt[8];
  __shared__ int lbase[8];
  const int wv = threadIdx.x >> 6, lane = threadIdx.x & 63;
  if (threadIdx.x < 8) lcnt[threadIdx.x] = 0;
  __syncthreads();

  for (int i = 0; i < 16; i++) {
    const int tl = wv * 16 + i;
    const int t = blockIdx.x * 64 + tl;
    const float* xr = x + (size_t)t * HDIM + lane * 16;
    float4 xv[4];
#pragma unroll
    for (int j = 0; j < 4; j++) xv[j] = ((const float4*)xr)[j];

    bf16x8 v0, v1;
#pragma unroll
    for (int j = 0; j < 8; j++) v0[j] = (__bf16)((const float*)xv)[j];
#pragma unroll
    for (int j = 0; j < 8; j++) v1[j] = (__bf16)((const float*)xv)[j + 8];
    bf16x8* xbo = (bf16x8*)(xb + (size_t)t * HDIM + lane * 16);
    xbo[0] = v0;
    xbo[1] = v1;

    float acc[8];
#pragma unroll
    for (int e = 0; e < 8; e++) {
      const float4* gp = (const float4*)(gw + e * HDIM + lane * 16);
      float s = 0.f;
#pragma unroll
      for (int j = 0; j < 4; j++) {
        float4 g = gp[j];
        s += xv[j].x * g.x + xv[j].y * g.y + xv[j].z * g.z + xv[j].w * g.w;
      }
      acc[e] = s;
    }
#pragma unroll
    for (int d = 32; d >= 1; d >>= 1) {
#pragma unroll
      for (int e = 0; e < 8; e++) acc[e] += __shfl_xor(acc[e], d, 64);
    }
    if (lane == 0) {
      float mx = acc[0];
#pragma unroll
      for (int e = 1; e < 8; e++) mx = fmaxf(mx, acc[e]);
      float p[8], Z = 0.f;
#pragma unroll
      for (int e = 0; e < 8; e++) {
        p[e] = expf(acc[e] - mx);
        Z += p[e];
      }
#pragma unroll
      for (int e = 0; e < 8; e++) p[e] /= Z;
      int i1 = 0;
#pragma unroll
      for (int e = 1; e < 8; e++)
        if (p[e] > p[i1]) i1 = e;
      int i2 = (i1 == 0) ? 1 : 0;
#pragma unroll
      for (int e = 0; e < 8; e++)
        if (e != i1 && p[e] > p[i2]) i2 = e;
      const float s12 = p[i1] + p[i2] + 1e-20f;
      s_eid[tl][0] = i1;
      s_eid[tl][1] = i2;
      s_wt[tl][0] = p[i1] / s12;
      s_wt[tl][1] = p[i2] / s12;
    }
  }
  __syncthreads();

  if (threadIdx.x < 64) {
    s_rank[threadIdx.x][0] = atomicAdd(&lcnt[s_eid[threadIdx.x][0]], 1);
    s_rank[threadIdx.x][1] = atomicAdd(&lcnt[s_eid[threadIdx.x][1]], 1);
  }
  __syncthreads();
  if (threadIdx.x < 8)
    lbase[threadIdx.x] =
        atomicAdd(&cnt[threadIdx.x * CNT_STRIDE], lcnt[threadIdx.x]);
  __syncthreads();
  if (threadIdx.x < 64) {
    const int t = blockIdx.x * 64 + threadIdx.x;
#pragma unroll
    for (int j = 0; j < 2; j++) {
      const int e = s_eid[threadIdx.x][j];
      const int slot = lbase[e] + s_rank[threadIdx.x][j];
      tok[e * T_TOTAL + slot] = t;
      wtl[e * T_TOTAL + slot] = s_wt[threadIdx.x][j];
      inv[t * 2 + j] = e * T_TOTAL + slot;
    }
  }
}

// ---------------------------------------------------------------------------
// Exclusive prefix scan of per-expert counts (8 values) -> base[e].
// ---------------------------------------------------------------------------
__global__ void k_scan(const int* __restrict__ cnt, int* __restrict__ base) {
  if (threadIdx.x == 0 && blockIdx.x == 0) {
    int s = 0;
#pragma unroll
    for (int e = 0; e < 8; e++) {
      base[e] = s;
      s += cnt[e * CNT_STRIDE];
    }
  }
}

// ---------------------------------------------------------------------------
// Transpose+cast (Wd): src fp32 [512][1024] -> out bf16 [b][1024][512].
// 64x64 tile; float4-coalesced loads; bf16x8 (16B/lane) stores, 8 lanes per
// 128B-contiguous output row segment.
// ---------------------------------------------------------------------------
__global__ __launch_bounds__(256) void k_transpose64(
    const float* __restrict__ w8, const float* __restrict__ w1,
    __bf16* __restrict__ out) {
  __shared__ float tile[64][65];
  const int b = blockIdx.z;
  const float* src = (b < 8) ? (w8 + (size_t)b * IDIM * HDIM) : w1;
  const int c0 = blockIdx.x * 64, r0 = blockIdx.y * 64;  // src rows r (512), cols c (1024)
  const int t = threadIdx.x;

#pragma unroll
  for (int j = 0; j < 4; j++) {
    const int rr = (t >> 4) + j * 16;
    const int cc = (t & 15) * 4;
    const float4 v = *(const float4*)(src + (size_t)(r0 + rr) * HDIM + c0 + cc);
    tile[rr][cc] = v.x;
    tile[rr][cc + 1] = v.y;
    tile[rr][cc + 2] = v.z;
    tile[rr][cc + 3] = v.w;
  }
  __syncthreads();

#pragma unroll
  for (int j = 0; j < 2; j++) {
    const int cidx = (t >> 3) + j * 32;   // out row (src col)
    const int rseg = (t & 7) * 8;         // out col start (src row)
    bf16x8 v;
#pragma unroll
    for (int k = 0; k < 8; k++) v[k] = (__bf16)tile[rseg + k][cidx];
    *(bf16x8*)(out + (size_t)b * HDIM * IDIM + (size_t)(c0 + cidx) * IDIM + r0 +
               rseg) = v;
  }
}

// ---------------------------------------------------------------------------
// Fused-GU transpose: src fp32 [b][1024 h][512 i] -> Wfu bf16 [b][1024 f][1024 h]
// fused row f(i) = 2*(i & ~15) + (i & 15) + u16off  (u16off: 0 for G, 16 for U)
// Same 64x64 tile scheme.
// ---------------------------------------------------------------------------
__global__ __launch_bounds__(256) void k_transpose_fuse64(
    const float* __restrict__ w8, const float* __restrict__ w1,
    __bf16* __restrict__ out, int u16off) {
  __shared__ float tile[64][65];
  const int b = blockIdx.z;
  const float* src = (b < 8) ? (w8 + (size_t)b * HDIM * IDIM) : w1;
  const int c0 = blockIdx.x * 64, r0 = blockIdx.y * 64;  // src rows h (1024), cols i (512)
  const int t = threadIdx.x;

#pragma unroll
  for (int j = 0; j < 4; j++) {
    const int rr = (t >> 4) + j * 16;
    const int cc = (t & 15) * 4;
    const float4 v = *(const float4*)(src + (size_t)(r0 + rr) * IDIM + c0 + cc);
    tile[rr][cc] = v.x;
    tile[rr][cc + 1] = v.y;
    tile[rr][cc + 2] = v.z;
    tile[rr][cc + 3] = v.w;
  }
  __syncthreads();

#pragma unroll
  for (int j = 0; j < 2; j++) {
    const int cidx = (t >> 3) + j * 32;  // i-local
    const int rseg = (t & 7) * 8;        // h-local start
    const int ic = c0 + cidx;
    const int f = 2 * (ic & ~15) + (ic & 15) + u16off;
    bf16x8 v;
#pragma unroll
    for (int k = 0; k < 8; k++) v[k] = (__bf16)tile[rseg + k][cidx];
    *(bf16x8*)(out + (size_t)b * 1024 * HDIM + (size_t)f * HDIM + r0 + rseg) = v;
  }
}

// ---------------------------------------------------------------------------
// Phase A: one GEMM [slots x 128 fused cols], K=H. zbase splits routed(0..7)
// and shared(8) into separate dispatches (profiling visibility).
// acc[im][2p]=G, acc[im][2p+1]=U for i-col = (n0+wn)/2 + p*16 + l16.
// ---------------------------------------------------------------------------
__global__ __launch_bounds__(256, 2) void k_gu(
    const __bf16* __restrict__ xb, const __bf16* __restrict__ Wfu,
    const int* __restrict__ tok, const float* __restrict__ wtl,
    const int* __restrict__ cnt, __bf16* __restrict__ inter, int zbase) {
  const int e = blockIdx.z + zbase;
  const bool se = (e == 8);
  const int cnt_e = se ? T_TOTAL : cnt[e * CNT_STRIDE];
  const int m0 = blockIdx.x * 128;
  if (m0 >= cnt_e) return;  // uniform early-exit before any barrier

  __shared__ __bf16 sA[128][64];
  __shared__ __bf16 sB[128][64];
  const int tid = threadIdx.x, w = tid >> 6, lane = tid & 63;
  const int n0 = blockIdx.y * 128;  // fused-row base (0..896)
  const int quad = lane >> 4, l16 = lane & 15;
  const int wm = (w & 1) * 64, wn = (w >> 1) * 64;

  // staging: 256 thr x 16B = 4KB/shot = 32 rows of 128B; 4 shots per buffer
  const int sr = tid >> 3;                     // row within shot
  const int scs = ((tid & 7) ^ (sr & 7)) * 8;  // swizzled source offset (elems)
  const __bf16* ap[4];
  const __bf16* bp[4];
#pragma unroll
  for (int sh = 0; sh < 4; sh++) {
    int s = m0 + sh * 32 + sr;
    if (s > cnt_e - 1) s = cnt_e - 1;
    const int t = se ? s : tok[e * T_TOTAL + s];
    ap[sh] = xb + (size_t)t * HDIM + scs;
    bp[sh] = Wfu + ((size_t)e * 1024 + n0 + sh * 32 + sr) * HDIM + scs;
  }
  char* const la = (char*)sA + w * 1024;  // +lane*16 implicit in global_load_lds
  char* const lb = (char*)sB + w * 1024;

  f32x4 acc[4][4];
#pragma unroll
  for (int im = 0; im < 4; im++)
#pragma unroll
    for (int in = 0; in < 4; in++) acc[im][in] = {0.f, 0.f, 0.f, 0.f};

  for (int k = 0; k < HDIM; k += 64) {
    __syncthreads();
#pragma unroll
    for (int sh = 0; sh < 4; sh++) {
      load_lds16(ap[sh], la + sh * 4096);
      load_lds16(bp[sh], lb + sh * 4096);
      ap[sh] += 64;
      bp[sh] += 64;
    }
    __syncthreads();
#pragma unroll
    for (int kh = 0; kh < 2; kh++) {
      bf16x8 af[4], bfr[4];
#pragma unroll
      for (int i = 0; i < 4; i++) {
        const int ra = wm + i * 16 + l16;
        af[i] = *(const bf16x8*)((const char*)sA + ra * 128 +
                                 ((kh * 4 + quad) ^ (ra & 7)) * 16);
        const int rb = wn + i * 16 + l16;
        bfr[i] = *(const bf16x8*)((const char*)sB + rb * 128 +
                                  ((kh * 4 + quad) ^ (rb & 7)) * 16);
      }
#pragma unroll
      for (int im = 0; im < 4; im++)
#pragma unroll
        for (int in = 0; in < 4; in++)
          acc[im][in] = mfma_bf16(af[im], bfr[in], acc[im][in]);
    }
  }

  // epilogue: C/D col=lane&15, row=quad*4+r; G/U pairs in even/odd n-frags
#pragma unroll
  for (int im = 0; im < 4; im++) {
#pragma unroll
    for (int r = 0; r < 4; r++) {
      const int slot = m0 + wm + im * 16 + quad * 4 + r;
      if (slot < cnt_e) {
        const float wt = se ? 1.0f : wtl[e * T_TOTAL + slot];
        __bf16* op =
            inter + ((size_t)e * T_TOTAL + slot) * IDIM + ((n0 + wn) >> 1) + l16;
#pragma unroll
        for (int p = 0; p < 2; p++) {
          const float g = acc[im][2 * p][r];
          const float u = acc[im][2 * p + 1][r];
          const float v =
              wt * u * 0.5f * g * (1.0f + erff(g * 0.70710678118654752f));
          op[p * 16] = (__bf16)v;
        }
      }
    }
  }
}

// ---------------------------------------------------------------------------
// Phase B routed, STORE version: per expert e, gathered GEMM
// inter[e][0..cnt) @ Wd[e] -> dense fp32 rows yb[base[e]+slot][H]. No atomics.
// ---------------------------------------------------------------------------
__global__ __launch_bounds__(256, 2) void k_down_rs(
    const __bf16* __restrict__ inter, const __bf16* __restrict__ WdT,
    const int* __restrict__ cnt, const int* __restrict__ base,
    float* __restrict__ yb) {
  const int e = blockIdx.z;
  const int cnt_e = cnt[e * CNT_STRIDE];
  const int m0 = blockIdx.x * 128;
  if (m0 >= cnt_e) return;
  const int rowb = base[e];

  __shared__ __bf16 sA[128][64];
  __shared__ __bf16 sB[128][64];
  const int tid = threadIdx.x, w = tid >> 6, lane = tid & 63;
  const int n0 = blockIdx.y * 128;
  const int quad = lane >> 4, l16 = lane & 15;
  const int wm = (w & 1) * 64, wn = (w >> 1) * 64;

  const int sr = tid >> 3;
  const int scs = ((tid & 7) ^ (sr & 7)) * 8;
  const __bf16* ap[4];
  const __bf16* bp[4];
#pragma unroll
  for (int sh = 0; sh < 4; sh++) {
    int s = m0 + sh * 32 + sr;
    if (s > cnt_e - 1) s = cnt_e - 1;
    ap[sh] = inter + ((size_t)e * T_TOTAL + s) * IDIM + scs;
    bp[sh] = WdT + ((size_t)e * HDIM + n0 + sh * 32 + sr) * IDIM + scs;
  }
  char* const la = (char*)sA + w * 1024;
  char* const lb = (char*)sB + w * 1024;

  f32x4 acc[4][4];
#pragma unroll
  for (int im = 0; im < 4; im++)
#pragma unroll
    for (int in = 0; in < 4; in++) acc[im][in] = {0.f, 0.f, 0.f, 0.f};

  for (int k = 0; k < IDIM; k += 64) {
    __syncthreads();
#pragma unroll
    for (int sh = 0; sh < 4; sh++) {
      load_lds16(ap[sh], la + sh * 4096);
      load_lds16(bp[sh], lb + sh * 4096);
      ap[sh] += 64;
      bp[sh] += 64;
    }
    __syncthreads();
#pragma unroll
    for (int kh = 0; kh < 2; kh++) {
      bf16x8 af[4], bfr[4];
#pragma unroll
      for (int i = 0; i < 4; i++) {
        const int ra = wm + i * 16 + l16;
        af[i] = *(const bf16x8*)((const char*)sA + ra * 128 +
                                 ((kh * 4 + quad) ^ (ra & 7)) * 16);
        const int rb = wn + i * 16 + l16;
        bfr[i] = *(const bf16x8*)((const char*)sB + rb * 128 +
                                  ((kh * 4 + quad) ^ (rb & 7)) * 16);
      }
#pragma unroll
      for (int im = 0; im < 4; im++)
#pragma unroll
        for (int in = 0; in < 4; in++)
          acc[im][in] = mfma_bf16(af[im], bfr[in], acc[im][in]);
    }
  }

#pragma unroll
  for (int im = 0; im < 4; im++) {
#pragma unroll
    for (int r = 0; r < 4; r++) {
      const int slot = m0 + wm + im * 16 + quad * 4 + r;
      if (slot < cnt_e) {
        float* op = yb + (size_t)(rowb + slot) * HDIM + n0 + wn + l16;
#pragma unroll
        for (int in = 0; in < 4; in++) op[in * 16] = acc[im][in][r];
      }
    }
  }
}

// ---------------------------------------------------------------------------
// Phase B shared + combine: out[t] = inter[8] @ Wd[8] + yb[row1(t)] + yb[row2(t)]
// Pure stores; routed rows gathered in the GEMM epilogue (hidden under GEMM).
// Runs after k_down_rs.
// ---------------------------------------------------------------------------
__global__ __launch_bounds__(256, 2) void k_down_sc(
    const __bf16* __restrict__ iA, const __bf16* __restrict__ wB,
    const float* __restrict__ yb, const int* __restrict__ inv,
    const int* __restrict__ base, float* __restrict__ out) {
  __shared__ __bf16 sA[128][64];
  __shared__ __bf16 sB[128][64];
  const int tid = threadIdx.x, w = tid >> 6, lane = tid & 63;
  const int m0 = blockIdx.x * 128, n0 = blockIdx.y * 128;
  const int quad = lane >> 4, l16 = lane & 15;
  const int wm = (w & 1) * 64, wn = (w >> 1) * 64;

  const int sr = tid >> 3;
  const int scs = ((tid & 7) ^ (sr & 7)) * 8;
  const __bf16* ap[4];
  const __bf16* bp[4];
#pragma unroll
  for (int sh = 0; sh < 4; sh++) {
    ap[sh] = iA + (size_t)(m0 + sh * 32 + sr) * IDIM + scs;
    bp[sh] = wB + (size_t)(n0 + sh * 32 + sr) * IDIM + scs;
  }
  char* const la = (char*)sA + w * 1024;
  char* const lb = (char*)sB + w * 1024;

  f32x4 acc[4][4];
#pragma unroll
  for (int im = 0; im < 4; im++)
#pragma unroll
    for (int in = 0; in < 4; in++) acc[im][in] = {0.f, 0.f, 0.f, 0.f};

  for (int k = 0; k < IDIM; k += 64) {
    __syncthreads();
#pragma unroll
    for (int sh = 0; sh < 4; sh++) {
      load_lds16(ap[sh], la + sh * 4096);
      load_lds16(bp[sh], lb + sh * 4096);
      ap[sh] += 64;
      bp[sh] += 64;
    }
    __syncthreads();
#pragma unroll
    for (int kh = 0; kh < 2; kh++) {
      bf16x8 af[4], bfr[4];
#pragma unroll
      for (int i = 0; i < 4; i++) {
        const int ra = wm + i * 16 + l16;
        af[i] = *(const bf16x8*)((const char*)sA + ra * 128 +
                                 ((kh * 4 + quad) ^ (ra & 7)) * 16);
        const int rb = wn + i * 16 + l16;
        bfr[i] = *(const bf16x8*)((const char*)sB + rb * 128 +
                                  ((kh * 4 + quad) ^ (rb & 7)) * 16);
      }
#pragma unroll
      for (int im = 0; im < 4; im++)
#pragma unroll
        for (int in = 0; in < 4; in++)
          acc[im][in] = mfma_bf16(af[im], bfr[in], acc[im][in]);
    }
  }

#pragma unroll
  for (int im = 0; im < 4; im++) {
#pragma unroll
    for (int r = 0; r < 4; r++) {
      const int t = m0 + wm + im * 16 + quad * 4 + r;
      const int v1 = inv[2 * t], v2 = inv[2 * t + 1];
      const int r1 = base[v1 >> 14] + (v1 & (T_TOTAL - 1));
      const int r2 = base[v2 >> 14] + (v2 & (T_TOTAL - 1));
      const float* y1 = yb + (size_t)r1 * HDIM + n0 + wn + l16;
      const float* y2 = yb + (size_t)r2 * HDIM + n0 + wn + l16;
      float* op = out + (size_t)t * HDIM + n0 + wn + l16;
#pragma unroll
      for (int in = 0; in < 4; in++)
        op[in * 16] = acc[im][in][r] + y1[in * 16] + y2[in * 16];
    }
  }
}

// ---------------------------------------------------------------------------
// Fallback path (ws too small for yb): shared GEMM plain stores, then routed
// atomic scatter-add (round-4 behavior).
// ---------------------------------------------------------------------------
__global__ __launch_bounds__(256, 2) void k_down_s(const __bf16* __restrict__ iA,
                                                   const __bf16* __restrict__ wB,
                                                   float* __restrict__ out) {
  __shared__ __bf16 sA[128][64];
  __shared__ __bf16 sB[128][64];
  const int tid = threadIdx.x, w = tid >> 6, lane = tid & 63;
  const int m0 = blockIdx.x * 128, n0 = blockIdx.y * 128;
  const int quad = lane >> 4, l16 = lane & 15;
  const int wm = (w & 1) * 64, wn = (w >> 1) * 64;

  const int sr = tid >> 3;
  const int scs = ((tid & 7) ^ (sr & 7)) * 8;
  const __bf16* ap[4];
  const __bf16* bp[4];
#pragma unroll
  for (int sh = 0; sh < 4; sh++) {
    ap[sh] = iA + (size_t)(m0 + sh * 32 + sr) * IDIM + scs;
    bp[sh] = wB + (size_t)(n0 + sh * 32 + sr) * IDIM + scs;
  }
  char* const la = (char*)sA + w * 1024;
  char* const lb = (char*)sB + w * 1024;

  f32x4 acc[4][4];
#pragma unroll
  for (int im = 0; im < 4; im++)
#pragma unroll
    for (int in = 0; in < 4; in++) acc[im][in] = {0.f, 0.f, 0.f, 0.f};

  for (int k = 0; k < IDIM; k += 64) {
    __syncthreads();
#pragma unroll
    for (int sh = 0; sh < 4; sh++) {
      load_lds16(ap[sh], la + sh * 4096);
      load_lds16(bp[sh], lb + sh * 4096);
      ap[sh] += 64;
      bp[sh] += 64;
    }
    __syncthreads();
#pragma unroll
    for (int kh = 0; kh < 2; kh++) {
      bf16x8 af[4], bfr[4];
#pragma unroll
      for (int i = 0; i < 4; i++) {
        const int ra = wm + i * 16 + l16;
        af[i] = *(const bf16x8*)((const char*)sA + ra * 128 +
                                 ((kh * 4 + quad) ^ (ra & 7)) * 16);
        const int rb = wn + i * 16 + l16;
        bfr[i] = *(const bf16x8*)((const char*)sB + rb * 128 +
                                  ((kh * 4 + quad) ^ (rb & 7)) * 16);
      }
#pragma unroll
      for (int im = 0; im < 4; im++)
#pragma unroll
        for (int in = 0; in < 4; in++)
          acc[im][in] = mfma_bf16(af[im], bfr[in], acc[im][in]);
    }
  }

#pragma unroll
  for (int im = 0; im < 4; im++) {
#pragma unroll
    for (int r = 0; r < 4; r++) {
      const int t = m0 + wm + im * 16 + quad * 4 + r;
#pragma unroll
      for (int in = 0; in < 4; in++)
        out[(size_t)t * HDIM + n0 + wn + in * 16 + l16] = acc[im][in][r];
    }
  }
}

__global__ __launch_bounds__(256, 2) void k_down_r(
    const __bf16* __restrict__ inter, const __bf16* __restrict__ WdT,
    const int* __restrict__ tok, const int* __restrict__ cnt,
    float* __restrict__ out) {
  const int e = blockIdx.z;
  const int cnt_e = cnt[e * CNT_STRIDE];
  const int m0 = blockIdx.x * 128;
  if (m0 >= cnt_e) return;

  __shared__ __bf16 sA[128][64];
  __shared__ __bf16 sB[128][64];
  const int tid = threadIdx.x, w = tid >> 6, lane = tid & 63;
  const int n0 = blockIdx.y * 128;
  const int quad = lane >> 4, l16 = lane & 15;
  const int wm = (w & 1) * 64, wn = (w >> 1) * 64;

  const int sr = tid >> 3;
  const int scs = ((tid & 7) ^ (sr & 7)) * 8;
  const __bf16* ap[4];
  const __bf16* bp[4];
#pragma unroll
  for (int sh = 0; sh < 4; sh++) {
    int s = m0 + sh * 32 + sr;
    if (s > cnt_e - 1) s = cnt_e - 1;
    ap[sh] = inter + ((size_t)e * T_TOTAL + s) * IDIM + scs;
    bp[sh] = WdT + ((size_t)e * HDIM + n0 + sh * 32 + sr) * IDIM + scs;
  }
  char* const la = (char*)sA + w * 1024;
  char* const lb = (char*)sB + w * 1024;

  f32x4 acc[4][4];
#pragma unroll
  for (int im = 0; im < 4; im++)
#pragma unroll
    for (int in = 0; in < 4; in++) acc[im][in] = {0.f, 0.f, 0.f, 0.f};

  for (int k = 0; k < IDIM; k += 64) {
    __syncthreads();
#pragma unroll
    for (int sh = 0; sh < 4; sh++) {
      load_lds16(ap[sh], la + sh * 4096);
      load_lds16(bp[sh], lb + sh * 4096);
      ap[sh] += 64;
      bp[sh] += 64;
    }
    __syncthreads();
#pragma unroll
    for (int kh = 0; kh < 2; kh++) {
      bf16x8 af[4], bfr[4];
#pragma unroll
      for (int i = 0; i < 4; i++) {
        const int ra = wm + i * 16 + l16;
        af[i] = *(const bf16x8*)((const char*)sA + ra * 128 +
                                 ((kh * 4 + quad) ^ (ra & 7)) * 16);
        const int rb = wn + i * 16 + l16;
        bfr[i] = *(const bf16x8*)((const char*)sB + rb * 128 +
                                  ((kh * 4 + quad) ^ (rb & 7)) * 16);
      }
#pragma unroll
      for (int im = 0; im < 4; im++)
#pragma unroll
        for (int in = 0; in < 4; in++)
          acc[im][in] = mfma_bf16(af[im], bfr[in], acc[im][in]);
    }
  }

#pragma unroll
  for (int im = 0; im < 4; im++) {
#pragma unroll
    for (int r = 0; r < 4; r++) {
      const int slot = m0 + wm + im * 16 + quad * 4 + r;
      if (slot < cnt_e) {
        const int t = tok[e * T_TOTAL + slot];
#pragma unroll
        for (int in = 0; in < 4; in++)
          atomicAdd(&out[(size_t)t * HDIM + n0 + wn + in * 16 + l16],
                    acc[im][in][r]);
      }
    }
  }
}

// ---------------------------------------------------------------------------
extern "C" void kernel_launch(void* const* d_in, const int* in_sizes, int n_in,
                              void* d_out, int out_size, void* d_ws,
                              size_t ws_size, hipStream_t stream) {
  const float* x = (const float*)d_in[0];
  const float* gw = (const float*)d_in[1];
  const float* Wg = (const float*)d_in[2];
  const float* Wu = (const float*)d_in[3];
  const float* Wd = (const float*)d_in[4];
  const float* sWg = (const float*)d_in[5];
  const float* sWu = (const float*)d_in[6];
  const float* sWd = (const float*)d_in[7];
  float* out = (float*)d_out;

  char* ws = (char*)d_ws;
  size_t off = 0;
  auto alloc = [&](size_t n) {
    char* p = ws + off;
    off += (n + 255) & ~(size_t)255;
    return p;
  };
  __bf16* xb = (__bf16*)alloc((size_t)T_TOTAL * HDIM * 2);          // 33.5 MB
  __bf16* Wfu = (__bf16*)alloc((size_t)NE * 1024 * HDIM * 2);       // 18.9 MB
  __bf16* WdT = (__bf16*)alloc((size_t)NE * HDIM * IDIM * 2);       // 9.4 MB
  int* tok = (int*)alloc((size_t)8 * T_TOTAL * 4);                  // 512 KB
  float* wtl = (float*)alloc((size_t)8 * T_TOTAL * 4);              // 512 KB
  int* cnt = (int*)alloc(8 * CNT_STRIDE * 4);
  int* inv = (int*)alloc((size_t)T_TOTAL * 2 * 4);                  // 128 KB
  int* base = (int*)alloc(16 * 4);
  __bf16* inter = (__bf16*)alloc((size_t)NE * T_TOTAL * IDIM * 2);  // 151 MB

  // Packed routed down-proj output: 2*T rows x H fp32 = 134 MB (optional).
  const size_t yb_bytes = (size_t)2 * T_TOTAL * HDIM * 4;
  const bool store_path = (off + yb_bytes) <= ws_size;
  float* yb = store_path ? (float*)alloc(yb_bytes) : nullptr;

  hipMemsetAsync(cnt, 0, 8 * CNT_STRIDE * 4, stream);

  k_gate<<<dim3(T_TOTAL / 64), dim3(256), 0, stream>>>(x, gw, xb, tok, wtl,
                                                       cnt, inv);
  // Wg/sWg -> fused rows +0 (G), Wu/sWu -> fused rows +16 (U)
  k_transpose_fuse64<<<dim3(IDIM / 64, HDIM / 64, NE), dim3(256), 0, stream>>>(
      Wg, sWg, Wfu, 0);
  k_transpose_fuse64<<<dim3(IDIM / 64, HDIM / 64, NE), dim3(256), 0, stream>>>(
      Wu, sWu, Wfu, 16);
  // Wd [8][I][H] + sWd [I][H] -> WdT [9][H][I]
  k_transpose64<<<dim3(HDIM / 64, IDIM / 64, NE), dim3(256), 0, stream>>>(
      Wd, sWd, WdT);
  k_scan<<<dim3(1), dim3(64), 0, stream>>>(cnt, base);

  // Phase A: fused GU; routed (z=0..7) and shared (z=8) split for visibility.
  k_gu<<<dim3(T_TOTAL / 128, 1024 / 128, 8), dim3(256), 0, stream>>>(
      xb, Wfu, tok, wtl, cnt, inter, 0);
  k_gu<<<dim3(T_TOTAL / 128, 1024 / 128, 1), dim3(256), 0, stream>>>(
      xb, Wfu, tok, wtl, cnt, inter, 8);

  if (store_path) {
    // routed experts -> packed yb (no atomics), then shared GEMM + gather-add.
    k_down_rs<<<dim3(T_TOTAL / 128, HDIM / 128, 8), dim3(256), 0, stream>>>(
        inter, WdT, cnt, base, yb);
    k_down_sc<<<dim3(T_TOTAL / 128, HDIM / 128), dim3(256), 0, stream>>>(
        inter + (size_t)8 * T_TOTAL * IDIM, WdT + (size_t)8 * HDIM * IDIM, yb,
        inv, base, out);
  } else {
    // fallback: shared GEMM stores, routed atomic scatter-add
    k_down_s<<<dim3(T_TOTAL / 128, HDIM / 128), dim3(256), 0, stream>>>(
        inter + (size_t)8 * T_TOTAL * IDIM, WdT + (size_t)8 * HDIM * IDIM, out);
    k_down_r<<<dim3(T_TOTAL / 128, HDIM / 128, 8), dim3(256), 0, stream>>>(
        inter, WdT, tok, cnt, out);
  }
}

// Round 5
// 435.455 us; speedup vs baseline: 1.3100x; 1.1336x over previous
//
#include <hip/hip_runtime.h>
#include <hip/hip_bf16.h>
#include <math.h>

// ---------------------------------------------------------------------------
// DeepseekV2 MoE: T=16384 tokens, H=1024, E=8 routed (top-2) + 1 shared, I=512
// Round 9: make the no-atomic phase-B path actually fit in workspace.
//  - inter PACKED: routed rows = base[e]+slot (exactly 2T=32768 rows), shared
//    at rows 32768..49151 -> 151MB -> 50.3MB.
//  - yb (fp32, 134MB) ALIASES xb+Wfu (dead after k_gu; single stream orders
//    k_down_rs after k_gu). Peak ws = 60.9 + 134 = 195MB <= proven 214MB.
//  - k_down_rs: routed gathered GEMM -> packed yb rows, pure stores.
//    k_down_sc: shared GEMM + epilogue gathers token's two routed rows via
//    inv[] -> out = shared + y1 + y2. Replaces the 131us atomic k_down_r
//    (MfmaUtil 10%, VALU 6%, HBM 17% = RMW-serialization-bound).
//  - Atomic fallback retained behind a ws_size check.
// ---------------------------------------------------------------------------

#define T_TOTAL 16384
#define HDIM 1024
#define IDIM 512
#define NE 9  // 8 routed + 1 shared (expert index 8)
#define CNT_STRIDE 16
#define SH_BASE 32768  // packed-inter row where shared expert starts

typedef __bf16 bf16x8 __attribute__((ext_vector_type(8)));
typedef float f32x4 __attribute__((ext_vector_type(4)));

typedef __attribute__((address_space(1))) void gvoid_t;
typedef __attribute__((address_space(3))) void lvoid_t;

__device__ __forceinline__ void load_lds16(const void* g, void* l) {
  // 16B/lane; LDS dest = wave-uniform base + lane*16 (global src may scatter)
  __builtin_amdgcn_global_load_lds((const gvoid_t*)g, (lvoid_t*)l, 16, 0, 0);
}

__device__ __forceinline__ f32x4 mfma_bf16(bf16x8 a, bf16x8 b, f32x4 c) {
  return __builtin_amdgcn_mfma_f32_16x16x32_bf16(a, b, c, 0, 0, 0);
}

// ---------------------------------------------------------------------------
// Gate: block-aggregated slot assignment. Also writes inv[t*2+j] = e*16384+slot
// (T_TOTAL = 2^14 -> decode e = v>>14, slot = v&16383).
// ---------------------------------------------------------------------------
__global__ __launch_bounds__(256) void k_gate(const float* __restrict__ x,
                                              const float* __restrict__ gw,
                                              __bf16* __restrict__ xb,
                                              int* __restrict__ tok,
                                              float* __restrict__ wtl,
                                              int* __restrict__ cnt,
                                              int* __restrict__ inv) {
  __shared__ int s_eid[64][2];
  __shared__ float s_wt[64][2];
  __shared__ int s_rank[64][2];
  __shared__ int lcnt[8];
  __shared__ int lbase[8];
  const int wv = threadIdx.x >> 6, lane = threadIdx.x & 63;
  if (threadIdx.x < 8) lcnt[threadIdx.x] = 0;
  __syncthreads();

  for (int i = 0; i < 16; i++) {
    const int tl = wv * 16 + i;
    const int t = blockIdx.x * 64 + tl;
    const float* xr = x + (size_t)t * HDIM + lane * 16;
    float4 xv[4];
#pragma unroll
    for (int j = 0; j < 4; j++) xv[j] = ((const float4*)xr)[j];

    bf16x8 v0, v1;
#pragma unroll
    for (int j = 0; j < 8; j++) v0[j] = (__bf16)((const float*)xv)[j];
#pragma unroll
    for (int j = 0; j < 8; j++) v1[j] = (__bf16)((const float*)xv)[j + 8];
    bf16x8* xbo = (bf16x8*)(xb + (size_t)t * HDIM + lane * 16);
    xbo[0] = v0;
    xbo[1] = v1;

    float acc[8];
#pragma unroll
    for (int e = 0; e < 8; e++) {
      const float4* gp = (const float4*)(gw + e * HDIM + lane * 16);
      float s = 0.f;
#pragma unroll
      for (int j = 0; j < 4; j++) {
        float4 g = gp[j];
        s += xv[j].x * g.x + xv[j].y * g.y + xv[j].z * g.z + xv[j].w * g.w;
      }
      acc[e] = s;
    }
#pragma unroll
    for (int d = 32; d >= 1; d >>= 1) {
#pragma unroll
      for (int e = 0; e < 8; e++) acc[e] += __shfl_xor(acc[e], d, 64);
    }
    if (lane == 0) {
      float mx = acc[0];
#pragma unroll
      for (int e = 1; e < 8; e++) mx = fmaxf(mx, acc[e]);
      float p[8], Z = 0.f;
#pragma unroll
      for (int e = 0; e < 8; e++) {
        p[e] = expf(acc[e] - mx);
        Z += p[e];
      }
#pragma unroll
      for (int e = 0; e < 8; e++) p[e] /= Z;
      int i1 = 0;
#pragma unroll
      for (int e = 1; e < 8; e++)
        if (p[e] > p[i1]) i1 = e;
      int i2 = (i1 == 0) ? 1 : 0;
#pragma unroll
      for (int e = 0; e < 8; e++)
        if (e != i1 && p[e] > p[i2]) i2 = e;
      const float s12 = p[i1] + p[i2] + 1e-20f;
      s_eid[tl][0] = i1;
      s_eid[tl][1] = i2;
      s_wt[tl][0] = p[i1] / s12;
      s_wt[tl][1] = p[i2] / s12;
    }
  }
  __syncthreads();

  if (threadIdx.x < 64) {
    s_rank[threadIdx.x][0] = atomicAdd(&lcnt[s_eid[threadIdx.x][0]], 1);
    s_rank[threadIdx.x][1] = atomicAdd(&lcnt[s_eid[threadIdx.x][1]], 1);
  }
  __syncthreads();
  if (threadIdx.x < 8)
    lbase[threadIdx.x] =
        atomicAdd(&cnt[threadIdx.x * CNT_STRIDE], lcnt[threadIdx.x]);
  __syncthreads();
  if (threadIdx.x < 64) {
    const int t = blockIdx.x * 64 + threadIdx.x;
#pragma unroll
    for (int j = 0; j < 2; j++) {
      const int e = s_eid[threadIdx.x][j];
      const int slot = lbase[e] + s_rank[threadIdx.x][j];
      tok[e * T_TOTAL + slot] = t;
      wtl[e * T_TOTAL + slot] = s_wt[threadIdx.x][j];
      inv[t * 2 + j] = e * T_TOTAL + slot;
    }
  }
}

// ---------------------------------------------------------------------------
// Exclusive prefix scan of per-expert counts (8 values) -> base[e].
// ---------------------------------------------------------------------------
__global__ void k_scan(const int* __restrict__ cnt, int* __restrict__ base) {
  if (threadIdx.x == 0 && blockIdx.x == 0) {
    int s = 0;
#pragma unroll
    for (int e = 0; e < 8; e++) {
      base[e] = s;
      s += cnt[e * CNT_STRIDE];
    }
  }
}

// ---------------------------------------------------------------------------
// Transpose+cast (Wd): src fp32 [512][1024] -> out bf16 [b][1024][512].
// 64x64 tile; float4-coalesced loads; bf16x8 (16B/lane) stores.
// ---------------------------------------------------------------------------
__global__ __launch_bounds__(256) void k_transpose64(
    const float* __restrict__ w8, const float* __restrict__ w1,
    __bf16* __restrict__ out) {
  __shared__ float tile[64][65];
  const int b = blockIdx.z;
  const float* src = (b < 8) ? (w8 + (size_t)b * IDIM * HDIM) : w1;
  const int c0 = blockIdx.x * 64, r0 = blockIdx.y * 64;
  const int t = threadIdx.x;

#pragma unroll
  for (int j = 0; j < 4; j++) {
    const int rr = (t >> 4) + j * 16;
    const int cc = (t & 15) * 4;
    const float4 v = *(const float4*)(src + (size_t)(r0 + rr) * HDIM + c0 + cc);
    tile[rr][cc] = v.x;
    tile[rr][cc + 1] = v.y;
    tile[rr][cc + 2] = v.z;
    tile[rr][cc + 3] = v.w;
  }
  __syncthreads();

#pragma unroll
  for (int j = 0; j < 2; j++) {
    const int cidx = (t >> 3) + j * 32;  // out row (src col)
    const int rseg = (t & 7) * 8;        // out col start (src row)
    bf16x8 v;
#pragma unroll
    for (int k = 0; k < 8; k++) v[k] = (__bf16)tile[rseg + k][cidx];
    *(bf16x8*)(out + (size_t)b * HDIM * IDIM + (size_t)(c0 + cidx) * IDIM + r0 +
               rseg) = v;
  }
}

// ---------------------------------------------------------------------------
// Fused-GU transpose: src fp32 [b][1024 h][512 i] -> Wfu bf16 [b][1024 f][1024 h]
// fused row f(i) = 2*(i & ~15) + (i & 15) + u16off  (u16off: 0 for G, 16 for U)
// ---------------------------------------------------------------------------
__global__ __launch_bounds__(256) void k_transpose_fuse64(
    const float* __restrict__ w8, const float* __restrict__ w1,
    __bf16* __restrict__ out, int u16off) {
  __shared__ float tile[64][65];
  const int b = blockIdx.z;
  const float* src = (b < 8) ? (w8 + (size_t)b * HDIM * IDIM) : w1;
  const int c0 = blockIdx.x * 64, r0 = blockIdx.y * 64;
  const int t = threadIdx.x;

#pragma unroll
  for (int j = 0; j < 4; j++) {
    const int rr = (t >> 4) + j * 16;
    const int cc = (t & 15) * 4;
    const float4 v = *(const float4*)(src + (size_t)(r0 + rr) * IDIM + c0 + cc);
    tile[rr][cc] = v.x;
    tile[rr][cc + 1] = v.y;
    tile[rr][cc + 2] = v.z;
    tile[rr][cc + 3] = v.w;
  }
  __syncthreads();

#pragma unroll
  for (int j = 0; j < 2; j++) {
    const int cidx = (t >> 3) + j * 32;  // i-local
    const int rseg = (t & 7) * 8;        // h-local start
    const int ic = c0 + cidx;
    const int f = 2 * (ic & ~15) + (ic & 15) + u16off;
    bf16x8 v;
#pragma unroll
    for (int k = 0; k < 8; k++) v[k] = (__bf16)tile[rseg + k][cidx];
    *(bf16x8*)(out + (size_t)b * 1024 * HDIM + (size_t)f * HDIM + r0 + rseg) = v;
  }
}

// ---------------------------------------------------------------------------
// Phase A: one GEMM [slots x 128 fused cols], K=H. zbase splits routed(0..7)
// and shared(8). Output rows PACKED: routed base[e]+slot, shared SH_BASE+slot.
// acc[im][2p]=G, acc[im][2p+1]=U for i-col = (n0+wn)/2 + p*16 + l16.
// ---------------------------------------------------------------------------
__global__ __launch_bounds__(256, 2) void k_gu(
    const __bf16* __restrict__ xb, const __bf16* __restrict__ Wfu,
    const int* __restrict__ tok, const float* __restrict__ wtl,
    const int* __restrict__ cnt, const int* __restrict__ base,
    __bf16* __restrict__ inter, int zbase) {
  const int e = blockIdx.z + zbase;
  const bool se = (e == 8);
  const int cnt_e = se ? T_TOTAL : cnt[e * CNT_STRIDE];
  const int m0 = blockIdx.x * 128;
  if (m0 >= cnt_e) return;  // uniform early-exit before any barrier
  const int rowb = se ? SH_BASE : base[e];

  __shared__ __bf16 sA[128][64];
  __shared__ __bf16 sB[128][64];
  const int tid = threadIdx.x, w = tid >> 6, lane = tid & 63;
  const int n0 = blockIdx.y * 128;  // fused-row base (0..896)
  const int quad = lane >> 4, l16 = lane & 15;
  const int wm = (w & 1) * 64, wn = (w >> 1) * 64;

  // staging: 256 thr x 16B = 4KB/shot = 32 rows of 128B; 4 shots per buffer
  const int sr = tid >> 3;                     // row within shot
  const int scs = ((tid & 7) ^ (sr & 7)) * 8;  // swizzled source offset (elems)
  const __bf16* ap[4];
  const __bf16* bp[4];
#pragma unroll
  for (int sh = 0; sh < 4; sh++) {
    int s = m0 + sh * 32 + sr;
    if (s > cnt_e - 1) s = cnt_e - 1;
    const int t = se ? s : tok[e * T_TOTAL + s];
    ap[sh] = xb + (size_t)t * HDIM + scs;
    bp[sh] = Wfu + ((size_t)e * 1024 + n0 + sh * 32 + sr) * HDIM + scs;
  }
  char* const la = (char*)sA + w * 1024;  // +lane*16 implicit in global_load_lds
  char* const lb = (char*)sB + w * 1024;

  f32x4 acc[4][4];
#pragma unroll
  for (int im = 0; im < 4; im++)
#pragma unroll
    for (int in = 0; in < 4; in++) acc[im][in] = {0.f, 0.f, 0.f, 0.f};

  for (int k = 0; k < HDIM; k += 64) {
    __syncthreads();
#pragma unroll
    for (int sh = 0; sh < 4; sh++) {
      load_lds16(ap[sh], la + sh * 4096);
      load_lds16(bp[sh], lb + sh * 4096);
      ap[sh] += 64;
      bp[sh] += 64;
    }
    __syncthreads();
#pragma unroll
    for (int kh = 0; kh < 2; kh++) {
      bf16x8 af[4], bfr[4];
#pragma unroll
      for (int i = 0; i < 4; i++) {
        const int ra = wm + i * 16 + l16;
        af[i] = *(const bf16x8*)((const char*)sA + ra * 128 +
                                 ((kh * 4 + quad) ^ (ra & 7)) * 16);
        const int rb = wn + i * 16 + l16;
        bfr[i] = *(const bf16x8*)((const char*)sB + rb * 128 +
                                  ((kh * 4 + quad) ^ (rb & 7)) * 16);
      }
#pragma unroll
      for (int im = 0; im < 4; im++)
#pragma unroll
        for (int in = 0; in < 4; in++)
          acc[im][in] = mfma_bf16(af[im], bfr[in], acc[im][in]);
    }
  }

  // epilogue: C/D col=lane&15, row=quad*4+r; G/U pairs in even/odd n-frags
#pragma unroll
  for (int im = 0; im < 4; im++) {
#pragma unroll
    for (int r = 0; r < 4; r++) {
      const int slot = m0 + wm + im * 16 + quad * 4 + r;
      if (slot < cnt_e) {
        const float wt = se ? 1.0f : wtl[e * T_TOTAL + slot];
        __bf16* op = inter + ((size_t)(rowb + slot)) * IDIM +
                     ((n0 + wn) >> 1) + l16;
#pragma unroll
        for (int p = 0; p < 2; p++) {
          const float g = acc[im][2 * p][r];
          const float u = acc[im][2 * p + 1][r];
          const float v =
              wt * u * 0.5f * g * (1.0f + erff(g * 0.70710678118654752f));
          op[p * 16] = (__bf16)v;
        }
      }
    }
  }
}

// ---------------------------------------------------------------------------
// Phase B routed, STORE version: per expert e, gathered GEMM over packed inter
// rows [base[e], base[e]+cnt_e) @ Wd[e] -> fp32 rows yb[base[e]+slot][H].
// ---------------------------------------------------------------------------
__global__ __launch_bounds__(256, 2) void k_down_rs(
    const __bf16* __restrict__ inter, const __bf16* __restrict__ WdT,
    const int* __restrict__ cnt, const int* __restrict__ base,
    float* __restrict__ yb) {
  const int e = blockIdx.z;
  const int cnt_e = cnt[e * CNT_STRIDE];
  const int m0 = blockIdx.x * 128;
  if (m0 >= cnt_e) return;
  const int rowb = base[e];

  __shared__ __bf16 sA[128][64];
  __shared__ __bf16 sB[128][64];
  const int tid = threadIdx.x, w = tid >> 6, lane = tid & 63;
  const int n0 = blockIdx.y * 128;
  const int quad = lane >> 4, l16 = lane & 15;
  const int wm = (w & 1) * 64, wn = (w >> 1) * 64;

  const int sr = tid >> 3;
  const int scs = ((tid & 7) ^ (sr & 7)) * 8;
  const __bf16* ap[4];
  const __bf16* bp[4];
#pragma unroll
  for (int sh = 0; sh < 4; sh++) {
    int s = m0 + sh * 32 + sr;
    if (s > cnt_e - 1) s = cnt_e - 1;
    ap[sh] = inter + (size_t)(rowb + s) * IDIM + scs;
    bp[sh] = WdT + ((size_t)e * HDIM + n0 + sh * 32 + sr) * IDIM + scs;
  }
  char* const la = (char*)sA + w * 1024;
  char* const lb = (char*)sB + w * 1024;

  f32x4 acc[4][4];
#pragma unroll
  for (int im = 0; im < 4; im++)
#pragma unroll
    for (int in = 0; in < 4; in++) acc[im][in] = {0.f, 0.f, 0.f, 0.f};

  for (int k = 0; k < IDIM; k += 64) {
    __syncthreads();
#pragma unroll
    for (int sh = 0; sh < 4; sh++) {
      load_lds16(ap[sh], la + sh * 4096);
      load_lds16(bp[sh], lb + sh * 4096);
      ap[sh] += 64;
      bp[sh] += 64;
    }
    __syncthreads();
#pragma unroll
    for (int kh = 0; kh < 2; kh++) {
      bf16x8 af[4], bfr[4];
#pragma unroll
      for (int i = 0; i < 4; i++) {
        const int ra = wm + i * 16 + l16;
        af[i] = *(const bf16x8*)((const char*)sA + ra * 128 +
                                 ((kh * 4 + quad) ^ (ra & 7)) * 16);
        const int rb = wn + i * 16 + l16;
        bfr[i] = *(const bf16x8*)((const char*)sB + rb * 128 +
                                  ((kh * 4 + quad) ^ (rb & 7)) * 16);
      }
#pragma unroll
      for (int im = 0; im < 4; im++)
#pragma unroll
        for (int in = 0; in < 4; in++)
          acc[im][in] = mfma_bf16(af[im], bfr[in], acc[im][in]);
    }
  }

#pragma unroll
  for (int im = 0; im < 4; im++) {
#pragma unroll
    for (int r = 0; r < 4; r++) {
      const int slot = m0 + wm + im * 16 + quad * 4 + r;
      if (slot < cnt_e) {
        float* op = yb + (size_t)(rowb + slot) * HDIM + n0 + wn + l16;
#pragma unroll
        for (int in = 0; in < 4; in++) op[in * 16] = acc[im][in][r];
      }
    }
  }
}

// ---------------------------------------------------------------------------
// Phase B shared + combine: out[t] = inter[shared] @ sWd + yb[r1(t)] + yb[r2(t)]
// Routed rows gathered in the GEMM epilogue; pure stores.
// ---------------------------------------------------------------------------
__global__ __launch_bounds__(256, 2) void k_down_sc(
    const __bf16* __restrict__ iA, const __bf16* __restrict__ wB,
    const float* __restrict__ yb, const int* __restrict__ inv,
    const int* __restrict__ base, float* __restrict__ out) {
  __shared__ __bf16 sA[128][64];
  __shared__ __bf16 sB[128][64];
  const int tid = threadIdx.x, w = tid >> 6, lane = tid & 63;
  const int m0 = blockIdx.x * 128, n0 = blockIdx.y * 128;
  const int quad = lane >> 4, l16 = lane & 15;
  const int wm = (w & 1) * 64, wn = (w >> 1) * 64;

  const int sr = tid >> 3;
  const int scs = ((tid & 7) ^ (sr & 7)) * 8;
  const __bf16* ap[4];
  const __bf16* bp[4];
#pragma unroll
  for (int sh = 0; sh < 4; sh++) {
    ap[sh] = iA + (size_t)(m0 + sh * 32 + sr) * IDIM + scs;
    bp[sh] = wB + (size_t)(n0 + sh * 32 + sr) * IDIM + scs;
  }
  char* const la = (char*)sA + w * 1024;
  char* const lb = (char*)sB + w * 1024;

  f32x4 acc[4][4];
#pragma unroll
  for (int im = 0; im < 4; im++)
#pragma unroll
    for (int in = 0; in < 4; in++) acc[im][in] = {0.f, 0.f, 0.f, 0.f};

  for (int k = 0; k < IDIM; k += 64) {
    __syncthreads();
#pragma unroll
    for (int sh = 0; sh < 4; sh++) {
      load_lds16(ap[sh], la + sh * 4096);
      load_lds16(bp[sh], lb + sh * 4096);
      ap[sh] += 64;
      bp[sh] += 64;
    }
    __syncthreads();
#pragma unroll
    for (int kh = 0; kh < 2; kh++) {
      bf16x8 af[4], bfr[4];
#pragma unroll
      for (int i = 0; i < 4; i++) {
        const int ra = wm + i * 16 + l16;
        af[i] = *(const bf16x8*)((const char*)sA + ra * 128 +
                                 ((kh * 4 + quad) ^ (ra & 7)) * 16);
        const int rb = wn + i * 16 + l16;
        bfr[i] = *(const bf16x8*)((const char*)sB + rb * 128 +
                                  ((kh * 4 + quad) ^ (rb & 7)) * 16);
      }
#pragma unroll
      for (int im = 0; im < 4; im++)
#pragma unroll
        for (int in = 0; in < 4; in++)
          acc[im][in] = mfma_bf16(af[im], bfr[in], acc[im][in]);
    }
  }

#pragma unroll
  for (int im = 0; im < 4; im++) {
#pragma unroll
    for (int r = 0; r < 4; r++) {
      const int t = m0 + wm + im * 16 + quad * 4 + r;
      const int v1 = inv[2 * t], v2 = inv[2 * t + 1];
      const int r1 = base[v1 >> 14] + (v1 & (T_TOTAL - 1));
      const int r2 = base[v2 >> 14] + (v2 & (T_TOTAL - 1));
      const float* y1 = yb + (size_t)r1 * HDIM + n0 + wn + l16;
      const float* y2 = yb + (size_t)r2 * HDIM + n0 + wn + l16;
      float* op = out + (size_t)t * HDIM + n0 + wn + l16;
#pragma unroll
      for (int in = 0; in < 4; in++)
        op[in * 16] = acc[im][in][r] + y1[in * 16] + y2[in * 16];
    }
  }
}

// ---------------------------------------------------------------------------
// Fallback path (ws too small for yb): shared GEMM plain stores, then routed
// atomic scatter-add on packed inter.
// ---------------------------------------------------------------------------
__global__ __launch_bounds__(256, 2) void k_down_s(const __bf16* __restrict__ iA,
                                                   const __bf16* __restrict__ wB,
                                                   float* __restrict__ out) {
  __shared__ __bf16 sA[128][64];
  __shared__ __bf16 sB[128][64];
  const int tid = threadIdx.x, w = tid >> 6, lane = tid & 63;
  const int m0 = blockIdx.x * 128, n0 = blockIdx.y * 128;
  const int quad = lane >> 4, l16 = lane & 15;
  const int wm = (w & 1) * 64, wn = (w >> 1) * 64;

  const int sr = tid >> 3;
  const int scs = ((tid & 7) ^ (sr & 7)) * 8;
  const __bf16* ap[4];
  const __bf16* bp[4];
#pragma unroll
  for (int sh = 0; sh < 4; sh++) {
    ap[sh] = iA + (size_t)(m0 + sh * 32 + sr) * IDIM + scs;
    bp[sh] = wB + (size_t)(n0 + sh * 32 + sr) * IDIM + scs;
  }
  char* const la = (char*)sA + w * 1024;
  char* const lb = (char*)sB + w * 1024;

  f32x4 acc[4][4];
#pragma unroll
  for (int im = 0; im < 4; im++)
#pragma unroll
    for (int in = 0; in < 4; in++) acc[im][in] = {0.f, 0.f, 0.f, 0.f};

  for (int k = 0; k < IDIM; k += 64) {
    __syncthreads();
#pragma unroll
    for (int sh = 0; sh < 4; sh++) {
      load_lds16(ap[sh], la + sh * 4096);
      load_lds16(bp[sh], lb + sh * 4096);
      ap[sh] += 64;
      bp[sh] += 64;
    }
    __syncthreads();
#pragma unroll
    for (int kh = 0; kh < 2; kh++) {
      bf16x8 af[4], bfr[4];
#pragma unroll
      for (int i = 0; i < 4; i++) {
        const int ra = wm + i * 16 + l16;
        af[i] = *(const bf16x8*)((const char*)sA + ra * 128 +
                                 ((kh * 4 + quad) ^ (ra & 7)) * 16);
        const int rb = wn + i * 16 + l16;
        bfr[i] = *(const bf16x8*)((const char*)sB + rb * 128 +
                                  ((kh * 4 + quad) ^ (rb & 7)) * 16);
      }
#pragma unroll
      for (int im = 0; im < 4; im++)
#pragma unroll
        for (int in = 0; in < 4; in++)
          acc[im][in] = mfma_bf16(af[im], bfr[in], acc[im][in]);
    }
  }

#pragma unroll
  for (int im = 0; im < 4; im++) {
#pragma unroll
    for (int r = 0; r < 4; r++) {
      const int t = m0 + wm + im * 16 + quad * 4 + r;
#pragma unroll
      for (int in = 0; in < 4; in++)
        out[(size_t)t * HDIM + n0 + wn + in * 16 + l16] = acc[im][in][r];
    }
  }
}

__global__ __launch_bounds__(256, 2) void k_down_r(
    const __bf16* __restrict__ inter, const __bf16* __restrict__ WdT,
    const int* __restrict__ tok, const int* __restrict__ cnt,
    const int* __restrict__ base, float* __restrict__ out) {
  const int e = blockIdx.z;
  const int cnt_e = cnt[e * CNT_STRIDE];
  const int m0 = blockIdx.x * 128;
  if (m0 >= cnt_e) return;
  const int rowb = base[e];

  __shared__ __bf16 sA[128][64];
  __shared__ __bf16 sB[128][64];
  const int tid = threadIdx.x, w = tid >> 6, lane = tid & 63;
  const int n0 = blockIdx.y * 128;
  const int quad = lane >> 4, l16 = lane & 15;
  const int wm = (w & 1) * 64, wn = (w >> 1) * 64;

  const int sr = tid >> 3;
  const int scs = ((tid & 7) ^ (sr & 7)) * 8;
  const __bf16* ap[4];
  const __bf16* bp[4];
#pragma unroll
  for (int sh = 0; sh < 4; sh++) {
    int s = m0 + sh * 32 + sr;
    if (s > cnt_e - 1) s = cnt_e - 1;
    ap[sh] = inter + (size_t)(rowb + s) * IDIM + scs;
    bp[sh] = WdT + ((size_t)e * HDIM + n0 + sh * 32 + sr) * IDIM + scs;
  }
  char* const la = (char*)sA + w * 1024;
  char* const lb = (char*)sB + w * 1024;

  f32x4 acc[4][4];
#pragma unroll
  for (int im = 0; im < 4; im++)
#pragma unroll
    for (int in = 0; in < 4; in++) acc[im][in] = {0.f, 0.f, 0.f, 0.f};

  for (int k = 0; k < IDIM; k += 64) {
    __syncthreads();
#pragma unroll
    for (int sh = 0; sh < 4; sh++) {
      load_lds16(ap[sh], la + sh * 4096);
      load_lds16(bp[sh], lb + sh * 4096);
      ap[sh] += 64;
      bp[sh] += 64;
    }
    __syncthreads();
#pragma unroll
    for (int kh = 0; kh < 2; kh++) {
      bf16x8 af[4], bfr[4];
#pragma unroll
      for (int i = 0; i < 4; i++) {
        const int ra = wm + i * 16 + l16;
        af[i] = *(const bf16x8*)((const char*)sA + ra * 128 +
                                 ((kh * 4 + quad) ^ (ra & 7)) * 16);
        const int rb = wn + i * 16 + l16;
        bfr[i] = *(const bf16x8*)((const char*)sB + rb * 128 +
                                  ((kh * 4 + quad) ^ (rb & 7)) * 16);
      }
#pragma unroll
      for (int im = 0; im < 4; im++)
#pragma unroll
        for (int in = 0; in < 4; in++)
          acc[im][in] = mfma_bf16(af[im], bfr[in], acc[im][in]);
    }
  }

#pragma unroll
  for (int im = 0; im < 4; im++) {
#pragma unroll
    for (int r = 0; r < 4; r++) {
      const int slot = m0 + wm + im * 16 + quad * 4 + r;
      if (slot < cnt_e) {
        const int t = tok[e * T_TOTAL + slot];
#pragma unroll
        for (int in = 0; in < 4; in++)
          atomicAdd(&out[(size_t)t * HDIM + n0 + wn + in * 16 + l16],
                    acc[im][in][r]);
      }
    }
  }
}

// ---------------------------------------------------------------------------
extern "C" void kernel_launch(void* const* d_in, const int* in_sizes, int n_in,
                              void* d_out, int out_size, void* d_ws,
                              size_t ws_size, hipStream_t stream) {
  const float* x = (const float*)d_in[0];
  const float* gw = (const float*)d_in[1];
  const float* Wg = (const float*)d_in[2];
  const float* Wu = (const float*)d_in[3];
  const float* Wd = (const float*)d_in[4];
  const float* sWg = (const float*)d_in[5];
  const float* sWu = (const float*)d_in[6];
  const float* sWd = (const float*)d_in[7];
  float* out = (float*)d_out;

  char* ws = (char*)d_ws;
  size_t off = 0;
  auto alloc = [&](size_t n) {
    char* p = ws + off;
    off += (n + 255) & ~(size_t)255;
    return p;
  };
  // --- persistent through phase B ---
  __bf16* WdT = (__bf16*)alloc((size_t)NE * HDIM * IDIM * 2);       // 9.4 MB
  int* tok = (int*)alloc((size_t)8 * T_TOTAL * 4);                  // 512 KB
  float* wtl = (float*)alloc((size_t)8 * T_TOTAL * 4);              // 512 KB
  int* cnt = (int*)alloc(8 * CNT_STRIDE * 4);
  int* inv = (int*)alloc((size_t)T_TOTAL * 2 * 4);                  // 128 KB
  int* base = (int*)alloc(16 * 4);
  __bf16* inter = (__bf16*)alloc((size_t)(3 * T_TOTAL) * IDIM * 2); // 50.3 MB
  const size_t off_persist = off;                                   // ~60.9 MB
  // --- dead after k_gu (yb aliases this region) ---
  __bf16* xb = (__bf16*)alloc((size_t)T_TOTAL * HDIM * 2);          // 33.5 MB
  __bf16* Wfu = (__bf16*)alloc((size_t)NE * 1024 * HDIM * 2);       // 18.9 MB

  // Packed routed down-proj output: 2T rows x H fp32 = 134 MB, aliased over
  // xb+Wfu (stream order: k_down_rs writes only after k_gu's last xb read).
  const size_t yb_bytes = (size_t)2 * T_TOTAL * HDIM * 4;
  const bool store_path = (off_persist + yb_bytes) <= ws_size;  // needs 195 MB
  float* yb = (float*)(ws + off_persist);

  hipMemsetAsync(cnt, 0, 8 * CNT_STRIDE * 4, stream);

  k_gate<<<dim3(T_TOTAL / 64), dim3(256), 0, stream>>>(x, gw, xb, tok, wtl,
                                                       cnt, inv);
  // Wg/sWg -> fused rows +0 (G), Wu/sWu -> fused rows +16 (U)
  k_transpose_fuse64<<<dim3(IDIM / 64, HDIM / 64, NE), dim3(256), 0, stream>>>(
      Wg, sWg, Wfu, 0);
  k_transpose_fuse64<<<dim3(IDIM / 64, HDIM / 64, NE), dim3(256), 0, stream>>>(
      Wu, sWu, Wfu, 16);
  // Wd [8][I][H] + sWd [I][H] -> WdT [9][H][I]
  k_transpose64<<<dim3(HDIM / 64, IDIM / 64, NE), dim3(256), 0, stream>>>(
      Wd, sWd, WdT);
  k_scan<<<dim3(1), dim3(64), 0, stream>>>(cnt, base);

  // Phase A: fused GU into packed inter; routed (z=0..7) then shared (z=8).
  k_gu<<<dim3(T_TOTAL / 128, 1024 / 128, 8), dim3(256), 0, stream>>>(
      xb, Wfu, tok, wtl, cnt, base, inter, 0);
  k_gu<<<dim3(T_TOTAL / 128, 1024 / 128, 1), dim3(256), 0, stream>>>(
      xb, Wfu, tok, wtl, cnt, base, inter, 8);

  if (store_path) {
    // routed experts -> packed yb (no atomics), then shared GEMM + gather-add.
    k_down_rs<<<dim3(T_TOTAL / 128, HDIM / 128, 8), dim3(256), 0, stream>>>(
        inter, WdT, cnt, base, yb);
    k_down_sc<<<dim3(T_TOTAL / 128, HDIM / 128), dim3(256), 0, stream>>>(
        inter + (size_t)SH_BASE * IDIM, WdT + (size_t)8 * HDIM * IDIM, yb, inv,
        base, out);
  } else {
    // fallback: shared GEMM stores, routed atomic scatter-add
    k_down_s<<<dim3(T_TOTAL / 128, HDIM / 128), dim3(256), 0, stream>>>(
        inter + (size_t)SH_BASE * IDIM, WdT + (size_t)8 * HDIM * IDIM, out);
    k_down_r<<<dim3(T_TOTAL / 128, HDIM / 128, 8), dim3(256), 0, stream>>>(
        inter, WdT, tok, cnt, base, out);
  }
}